// Round 8
// baseline (204.008 us; speedup 1.0000x reference)
//
#include <hip/hip_runtime.h>
#include <hip/hip_bf16.h>

typedef __hip_bfloat16 bf16;
typedef __attribute__((ext_vector_type(8))) short bf16x8;
typedef __attribute__((ext_vector_type(4))) float f32x4;

#define T_SEQ 2048
#define NHEADS 16
#define DK 64
#define DMODEL 1024

__device__ inline void load_lds16(const void* g, void* l) {
    __builtin_amdgcn_global_load_lds((const __attribute__((address_space(1))) void*)g,
                                     (__attribute__((address_space(3))) void*)l, 16, 0, 0);
}

// ---------------- fp32 -> bf16 convert: x + all four weights, one launch ----
__global__ void cvt_all(const float* __restrict__ x,  const float* __restrict__ wq,
                        const float* __restrict__ wk, const float* __restrict__ wv,
                        const float* __restrict__ wo, bf16* __restrict__ xb,
                        bf16* __restrict__ wqkvb, bf16* __restrict__ wob) {
    int i = blockIdx.x * blockDim.x + threadIdx.x;   // 0 .. 2M-1 (float4 units)
    const float* src; bf16* dst; int off;
    if (i < (1 << 20)) { src = x; dst = xb; off = i; }
    else {
        int j = i - (1 << 20);
        int seg = j >> 18; off = j & ((1 << 18) - 1);
        src = (seg == 0) ? wq : (seg == 1) ? wk : (seg == 2) ? wv : wo;
        dst = (seg < 3) ? (wqkvb + ((size_t)seg << 20)) : wob;
    }
    float4 f = ((const float4*)src)[off];
    ushort4 o;
    o.x = __bfloat16_as_ushort(__float2bfloat16(f.x));
    o.y = __bfloat16_as_ushort(__float2bfloat16(f.y));
    o.z = __bfloat16_as_ushort(__float2bfloat16(f.z));
    o.w = __bfloat16_as_ushort(__float2bfloat16(f.w));
    ((ushort4*)dst)[off] = o;
}

// ---------------- GEMM1: qkv = x * Wqkv^T, fused RoPE + head split ----------
// v16 structure (BK=64, blk^(row&7) swizzle) — unchanged this round.
__global__ __launch_bounds__(256, 4) void gemm_qkv_rope(const bf16* __restrict__ A,
                                                        const bf16* __restrict__ B,
                                                        bf16* __restrict__ qb,
                                                        bf16* __restrict__ kb,
                                                        bf16* __restrict__ vt) {
    const int K = 1024;
    __shared__ bf16 As[128 * 64];
    __shared__ bf16 Bs[128 * 64];
    const int tid  = threadIdx.x;
    const int lane = tid & 63;
    const int wave = tid >> 6;
    const int l16  = lane & 15;
    const int quad = lane >> 4;
    const int wy = wave >> 1, wx = wave & 1;
    const int brow = blockIdx.y * 128;
    const int bcol = blockIdx.x * 128;
    const int sw0 = (quad ^ (l16 & 7)) * 8;
    const int sw1 = ((4 + quad) ^ (l16 & 7)) * 8;

    f32x4 acc[4][4] = {};

    for (int k0 = 0; k0 < K; k0 += 64) {
#pragma unroll
        for (int i = 0; i < 4; ++i) {
            int j   = tid + 256 * i;                  // 0..1023
            int row = j >> 3;
            int blk = (j & 7) ^ (row & 7);            // pre-swizzled source blk
            load_lds16(A + (size_t)(brow + row) * K + k0 + blk * 8, (char*)As + j * 16);
            load_lds16(B + (size_t)(bcol + row) * K + k0 + blk * 8, (char*)Bs + j * 16);
        }
        __syncthreads();
#pragma unroll
        for (int ks = 0; ks < 2; ++ks) {
            const int sw = ks ? sw1 : sw0;
            bf16x8 af[4], bq[4];
#pragma unroll
            for (int i = 0; i < 4; ++i)
                af[i] = *(const bf16x8*)(As + (wy * 64 + i * 16 + l16) * 64 + sw);
#pragma unroll
            for (int j = 0; j < 4; ++j)
                bq[j] = *(const bf16x8*)(Bs + (wx * 64 + j * 16 + l16) * 64 + sw);
#pragma unroll
            for (int i = 0; i < 4; ++i)
#pragma unroll
                for (int j = 0; j < 4; ++j)
                    acc[i][j] = __builtin_amdgcn_mfma_f32_16x16x32_bf16(af[i], bq[j], acc[i][j], 0, 0, 0);
        }
        __syncthreads();
    }
    const int seg = bcol >> 10;                       // uniform per block
    const int hh  = ((bcol & 1023) >> 6) + wx;        // head index
    if (seg < 2) {
        bf16* dst = seg ? kb : qb;
        // q pre-scaled so attn computes p = exp2(q'.k) directly
        const float osc = seg ? 1.0f : 0.18033688011112042f;  // log2(e)/8
#pragma unroll
        for (int j = 0; j < 4; ++j) {
            const int d = j * 16 + l16;               // dk within head
            const float inv = exp2f(-0.31143075889f * (float)(d >> 1));  // 1000^(-i/32)
#pragma unroll
            for (int i = 0; i < 4; ++i)
#pragma unroll
                for (int r = 0; r < 4; ++r) {
                    int row = brow + wy * 64 + i * 16 + quad * 4 + r;
                    int t = row & (T_SEQ - 1), bi = row >> 11;
                    float s, c;
                    __sincosf((float)t * inv, &s, &c);
                    float v = acc[i][j][r];
                    float p = __shfl_xor(v, 1);
                    float res = (l16 & 1) ? fmaf(p, s, v * c) : fmaf(-p, s, v * c);
                    dst[((size_t)(bi * NHEADS + hh) * T_SEQ + t) * DK + d] =
                        __float2bfloat16(res * osc);
                }
        }
    } else {
#pragma unroll
        for (int j = 0; j < 4; ++j) {
            const int d = j * 16 + l16;
#pragma unroll
            for (int i = 0; i < 4; ++i)
#pragma unroll
                for (int r = 0; r < 4; ++r) {
                    int row = brow + wy * 64 + i * 16 + quad * 4 + r;
                    int t = row & (T_SEQ - 1), bi = row >> 11;
                    vt[((size_t)(bi * NHEADS + hh) * DK + d) * T_SEQ + t] =
                        __float2bfloat16(acc[i][j][r]);
                }
        }
    }
}

// ---------------- GEMM: C[M,N] = A[M,K] * B[N,K]^T (fp32 out) ----------------
// v16 structure — unchanged this round.
__global__ __launch_bounds__(256, 4) void gemm_bt(const bf16* __restrict__ A,
                                                  const bf16* __restrict__ B,
                                                  float* __restrict__ C,
                                                  int M, int N, int K) {
    __shared__ bf16 As[128 * 64];
    __shared__ bf16 Bs[128 * 64];
    const int tid  = threadIdx.x;
    const int lane = tid & 63;
    const int wave = tid >> 6;
    const int l16  = lane & 15;
    const int quad = lane >> 4;
    const int wy = wave >> 1, wx = wave & 1;
    const int brow = blockIdx.y * 128;
    const int bcol = blockIdx.x * 128;
    const int sw0 = (quad ^ (l16 & 7)) * 8;
    const int sw1 = ((4 + quad) ^ (l16 & 7)) * 8;

    f32x4 acc[4][4] = {};

    for (int k0 = 0; k0 < K; k0 += 64) {
#pragma unroll
        for (int i = 0; i < 4; ++i) {
            int j   = tid + 256 * i;
            int row = j >> 3;
            int blk = (j & 7) ^ (row & 7);
            load_lds16(A + (size_t)(brow + row) * K + k0 + blk * 8, (char*)As + j * 16);
            load_lds16(B + (size_t)(bcol + row) * K + k0 + blk * 8, (char*)Bs + j * 16);
        }
        __syncthreads();
#pragma unroll
        for (int ks = 0; ks < 2; ++ks) {
            const int sw = ks ? sw1 : sw0;
            bf16x8 af[4], bq[4];
#pragma unroll
            for (int i = 0; i < 4; ++i)
                af[i] = *(const bf16x8*)(As + (wy * 64 + i * 16 + l16) * 64 + sw);
#pragma unroll
            for (int j = 0; j < 4; ++j)
                bq[j] = *(const bf16x8*)(Bs + (wx * 64 + j * 16 + l16) * 64 + sw);
#pragma unroll
            for (int i = 0; i < 4; ++i)
#pragma unroll
                for (int j = 0; j < 4; ++j)
                    acc[i][j] = __builtin_amdgcn_mfma_f32_16x16x32_bf16(af[i], bq[j], acc[i][j], 0, 0, 0);
        }
        __syncthreads();
    }
#pragma unroll
    for (int i = 0; i < 4; ++i)
#pragma unroll
        for (int j = 0; j < 4; ++j)
#pragma unroll
            for (int r = 0; r < 4; ++r) {
                int row = brow + wy * 64 + i * 16 + quad * 4 + r;
                int col = bcol + wx * 64 + j * 16 + l16;
                C[(size_t)row * N + col] = acc[i][j][r];
            }
}

// ---------------- flash attention v17: balanced 12-iter parcels -------------
// v12 body unchanged. Schedule: 272 iters/bh repartitioned into 24 parcels of
// <= 12 iters (21x12 + {10,6,4}); a parcel = up to 2 (tile,it0,it1) segments.
// With all 768 blocks co-resident, CU wall = max parcel (was 16, now 12).
// Tiles 0-5 stay atomic-free (full-tile, conc direct); tiles 6-15 split ->
// atomic region q in [768,2048) (Oacc/Lacc 1280 rows/bh). Segment encoding:
// tile<<10 | it0<<5 | it1 ; 0xFFFF = no second segment. Table ordered so each
// residency class {x, x+8, x+16} has at most one short parcel.
__constant__ unsigned short c_par[24][2] = {
    {    1,  4105},   // (t0 full) + (t4 full)          = 12
    { 1027,  3079},   // (t1 full) + (t3 full)          = 12
    { 5131, 0xFFFF},  // t5 full                        = 12
    { 6155, 0xFFFF},  // t6 it 0-11                     = 12
    { 7179, 0xFFFF},  // t7 it 0-11                     = 12
    { 8203, 0xFFFF},  // t8 it 0-11                     = 12
    { 9227, 0xFFFF},  // t9 it 0-11                     = 12
    {10251, 0xFFFF},  // t10 it 0-11                    = 12
    {11275, 0xFFFF},  // t11 it 0-11                    = 12
    {11671, 0xFFFF},  // t11 it 12-23                   = 12
    {12299, 0xFFFF},  // t12 it 0-11                    = 12
    {12695, 0xFFFF},  // t12 it 12-23                   = 12
    {13323, 0xFFFF},  // t13 it 0-11                    = 12
    {13719, 0xFFFF},  // t13 it 12-23                   = 12
    {14347, 0xFFFF},  // t14 it 0-11                    = 12
    {14743, 0xFFFF},  // t14 it 12-23                   = 12
    {15371, 0xFFFF},  // t15 it 0-11                    = 12
    {15767, 0xFFFF},  // t15 it 12-23                   = 12
    { 6541, 10645},   // t6 it 12-13 + t10 it 12-21     = 12
    { 7567,  9619},   // t7 it 12-15 + t9 it 12-19      = 12
    { 8593, 15133},   // t8 it 12-17 + t14 it 24-29     = 12
    { 2053, 0xFFFF},  // t2 full                        = 6
    {13081, 16159},   // t12 it 24-25 + t15 it 24-31    = 10
    {14107, 0xFFFF}}; // t13 it 24-27                   = 4

__global__ __launch_bounds__(256, 4) void attn_kernel(const bf16* __restrict__ qb,
                                                      const bf16* __restrict__ kb,
                                                      const bf16* __restrict__ vt,
                                                      float* __restrict__ Oacc,
                                                      float* __restrict__ Lacc,
                                                      bf16* __restrict__ conc) {
    __shared__ bf16 Ks[2][64 * 64];                // 2 x 8 KB
    __shared__ bf16 Vs[2][64 * 64];                // 2 x 8 KB
    __shared__ bf16 Pl[4][16 * 64];                // 8 KB (per-wave, shared g0/g1)
    const int bh = blockIdx.y;
    const int b = bh >> 4, h = bh & 15;

    const int tid = threadIdx.x;
    const int lane = tid & 63, wave = tid >> 6;
    const int l16 = lane & 15, quad = lane >> 4;

    const bf16* Qp = qb + (size_t)bh * T_SEQ * DK;
    const bf16* Kp = kb + (size_t)bh * T_SEQ * DK;
    const bf16* Vp = vt + (size_t)bh * DK * T_SEQ;
    char* Pw = (char*)&Pl[wave][0];

    // ones B-fragment for the l row-sum MFMA
    const short one_bits = 0x3F80;
    const bf16x8 ones = {one_bits, one_bits, one_bits, one_bits,
                         one_bits, one_bits, one_bits, one_bits};

    // stage row-major 64x64 tile with XOR-swizzled 16B col-blocks
    auto stage = [&](int bb, int k0) {
        int j = tid;
#pragma unroll
        for (int i = 0; i < 2; ++i, j += 256) {
            int row = j >> 3, cbl = (j & 7) ^ ((j >> 3) & 7);
            load_lds16(Kp + (size_t)(k0 + row) * DK + cbl * 8, (char*)Ks[bb] + j * 16);
        }
        j = tid;
#pragma unroll
        for (int i = 0; i < 2; ++i, j += 256) {
            int row = j >> 3, cbl = (j & 7) ^ ((j >> 3) & 7);
            load_lds16(Vp + (size_t)row * T_SEQ + k0 + cbl * 8, (char*)Vs[bb] + j * 16);
        }
    };

    const int sw0 = (quad ^ (l16 & 7)) * 8;
    const int sw1 = ((4 + quad) ^ (l16 & 7)) * 8;
    // P buffer addressing (bytes): row=l16 (128B), XOR-swizzled 16B blocks
    const int pw_wr_base = l16 * 128 + (quad & 1) * 8;   // + swizzled block
    const int pq = quad >> 1;

    for (int sg = 0; sg < 2; ++sg) {
        const unsigned int e = c_par[blockIdx.x][sg];
        if (e == 0xFFFF) break;
        const int tile = e >> 10;
        const int it0  = (e >> 5) & 31;
        const int it1  = e & 31;
        const bool partial = !(it0 == 0 && it1 == 2 * tile + 1);
        const int qbase = tile << 7;                   // 128 queries per tile
        const int qr0 = qbase + wave * 16;             // group0 query rows
        const int qr1 = qr0 + 64;                      // group1 query rows

        // Q as B-operand: n = query = l16, k = dk = quad*8+j (+32 per kstep)
        bf16x8 qf[2][2];
#pragma unroll
        for (int s = 0; s < 2; ++s) {
            qf[0][s] = *(const bf16x8*)(Qp + (size_t)(qr0 + l16) * DK + s * 32 + quad * 8);
            qf[1][s] = *(const bf16x8*)(Qp + (size_t)(qr1 + l16) * DK + s * 32 + quad * 8);
        }

        f32x4 o0[4] = {}, o1[4] = {};
        f32x4 ol0 = {}, ol1 = {};      // l row-sums (same C-rows as o*[j])

        if (sg) __syncthreads();       // seg-1 LDS reads done before re-staging
        int cur = 0;
        stage(0, it0 * 64);
        for (int it = it0; it <= it1; ++it) {
            __syncthreads();                      // drains DMA for cur + syncs waves
            if (it < it1) stage(cur ^ 1, (it + 1) * 64);

            const int k0 = it * 64;
            const bool skip0 = (k0 > qr0 + 15);             // wave-uniform
            const bool diag0 = (k0 + 63 > qr0) && !skip0;
            const bool diag1 = (k0 + 63 > qr1);             // skip1 never happens

            // S^T = K Q^T over 64 keys; kf fragments shared by both groups
            f32x4 s0[4] = {}, s1[4] = {};
            __builtin_amdgcn_s_setprio(1);
#pragma unroll
            for (int nt = 0; nt < 4; ++nt) {
                bf16x8 kf0 = *(const bf16x8*)(Ks[cur] + (nt * 16 + l16) * 64 + sw0);
                bf16x8 kf1 = *(const bf16x8*)(Ks[cur] + (nt * 16 + l16) * 64 + sw1);
                if (!skip0) {
                    s0[nt] = __builtin_amdgcn_mfma_f32_16x16x32_bf16(kf0, qf[0][0], s0[nt], 0, 0, 0);
                    s0[nt] = __builtin_amdgcn_mfma_f32_16x16x32_bf16(kf1, qf[0][1], s0[nt], 0, 0, 0);
                }
                s1[nt] = __builtin_amdgcn_mfma_f32_16x16x32_bf16(kf0, qf[1][0], s1[nt], 0, 0, 0);
                s1[nt] = __builtin_amdgcn_mfma_f32_16x16x32_bf16(kf1, qf[1][1], s1[nt], 0, 0, 0);
            }
            __builtin_amdgcn_s_setprio(0);

            // ---- group 0: exp -> P buffer -> PV (+ l-sum MFMA) ----
            if (!skip0) {
#pragma unroll
                for (int nt = 0; nt < 4; ++nt) {
                    union { bf16 hv[4]; uint2 u; } pk;
#pragma unroll
                    for (int r = 0; r < 4; ++r) {
                        float v = s0[nt][r];
                        if (diag0 && (k0 + nt * 16 + quad * 4 + r > qr0 + l16)) v = -30.0f;
                        pk.hv[r] = __float2bfloat16(exp2f(v));
                    }
                    *(uint2*)(Pw + pw_wr_base + (((nt * 2 + pq) ^ (l16 & 7)) << 4)) = pk.u;
                }
                __builtin_amdgcn_s_setprio(1);
#pragma unroll
                for (int ks = 0; ks < 2; ++ks) {
                    bf16x8 pf = *(const bf16x8*)(Pw + l16 * 128 + (((ks * 4 + quad) ^ (l16 & 7)) << 4));
                    const int sw = ks ? sw1 : sw0;
                    ol0 = __builtin_amdgcn_mfma_f32_16x16x32_bf16(pf, ones, ol0, 0, 0, 0);
#pragma unroll
                    for (int j = 0; j < 4; ++j) {
                        bf16x8 vf = *(const bf16x8*)(Vs[cur] + (j * 16 + l16) * 64 + sw);
                        o0[j] = __builtin_amdgcn_mfma_f32_16x16x32_bf16(pf, vf, o0[j], 0, 0, 0);
                    }
                }
                __builtin_amdgcn_s_setprio(0);
            }

            // ---- group 1: exp -> P buffer (per-wave DS pipe is in-order) ----
#pragma unroll
            for (int nt = 0; nt < 4; ++nt) {
                union { bf16 hv[4]; uint2 u; } pk;
#pragma unroll
                for (int r = 0; r < 4; ++r) {
                    float v = s1[nt][r];
                    if (diag1 && (k0 + nt * 16 + quad * 4 + r > qr1 + l16)) v = -30.0f;
                    pk.hv[r] = __float2bfloat16(exp2f(v));
                }
                *(uint2*)(Pw + pw_wr_base + (((nt * 2 + pq) ^ (l16 & 7)) << 4)) = pk.u;
            }
            __builtin_amdgcn_s_setprio(1);
#pragma unroll
            for (int ks = 0; ks < 2; ++ks) {
                bf16x8 pf = *(const bf16x8*)(Pw + l16 * 128 + (((ks * 4 + quad) ^ (l16 & 7)) << 4));
                const int sw = ks ? sw1 : sw0;
                ol1 = __builtin_amdgcn_mfma_f32_16x16x32_bf16(pf, ones, ol1, 0, 0, 0);
#pragma unroll
                for (int j = 0; j < 4; ++j) {
                    bf16x8 vf = *(const bf16x8*)(Vs[cur] + (j * 16 + l16) * 64 + sw);
                    o1[j] = __builtin_amdgcn_mfma_f32_16x16x32_bf16(pf, vf, o1[j], 0, 0, 0);
                }
            }
            __builtin_amdgcn_s_setprio(0);
            cur ^= 1;
        }

        // epilogue: ol*[r] is the full l for query qr + quad*4 + r
#pragma unroll
        for (int g = 0; g < 2; ++g) {
            const f32x4* op = g ? o1 : o0;
            const f32x4 lv = g ? ol1 : ol0;
            const int qr = g ? qr1 : qr0;
            if (!partial) {
#pragma unroll
                for (int r = 0; r < 4; ++r) {
                    float inv_l = 1.0f / lv[r];
                    int t = qr + quad * 4 + r;
#pragma unroll
                    for (int j = 0; j < 4; ++j)
                        conc[((size_t)b * T_SEQ + t) * DMODEL + h * DK + j * 16 + l16] =
                            __float2bfloat16(op[j][r] * inv_l);
                }
            } else {
#pragma unroll
                for (int r = 0; r < 4; ++r) {
                    int q = qr + quad * 4 + r;
                    if (l16 == 0)
                        atomicAdd(&Lacc[(size_t)bh * 1280 + q - 768], lv[r]);
                    float* Ob = Oacc + ((size_t)bh * 1280 + q - 768) * DK;
#pragma unroll
                    for (int j = 0; j < 4; ++j)
                        atomicAdd(&Ob[j * 16 + l16], op[j][r]);
                }
            }
        }
    }
}

// ---------------- normalize + concat (q in [768, 2048)) ---------------------
__global__ void attn_finalize(const float* __restrict__ Oacc, const float* __restrict__ Lacc,
                              bf16* __restrict__ conc) {
    int i4 = blockIdx.x * blockDim.x + threadIdx.x;   // float4 units
    if (i4 >= 32 * 1280 * 16) return;
    int bhq = i4 >> 4;          // bh*1280 + q7
    int d4  = i4 & 15;
    int bh = bhq / 1280, q7 = bhq - bh * 1280;
    int b = bh >> 4, h = bh & 15;
    int q = 768 + q7;
    float inv = 1.0f / Lacc[bhq];
    float4 o4 = ((const float4*)Oacc)[i4];
    ushort4 u;
    u.x = __bfloat16_as_ushort(__float2bfloat16(o4.x * inv));
    u.y = __bfloat16_as_ushort(__float2bfloat16(o4.y * inv));
    u.z = __bfloat16_as_ushort(__float2bfloat16(o4.z * inv));
    u.w = __bfloat16_as_ushort(__float2bfloat16(o4.w * inv));
    *(ushort4*)&conc[((size_t)(b * T_SEQ + q)) * DMODEL + h * DK + d4 * 4] = u;
}

extern "C" void kernel_launch(void* const* d_in, const int* in_sizes, int n_in,
                              void* d_out, int out_size, void* d_ws, size_t ws_size,
                              hipStream_t stream) {
    const float* x  = (const float*)d_in[0];
    const float* wq = (const float*)d_in[1];
    const float* wk = (const float*)d_in[2];
    const float* wv = (const float*)d_in[3];
    const float* wo = (const float*)d_in[4];
    float* out = (float*)d_out;

    char* ws = (char*)d_ws;
    bf16* xb    = (bf16*)(ws);                      // 8 MiB  (4096x1024)
    bf16* wqkvb = (bf16*)(ws + (8ull << 20));       // 6 MiB  (3072x1024)
    bf16* wob   = (bf16*)(ws + (14ull << 20));      // 2 MiB  (1024x1024)
    bf16* conc  = (bf16*)(ws + (16ull << 20));      // 8 MiB
    float* Oacc = (float*)(ws + (24ull << 20));     // 10 MiB (32 x 1280 x 64 f32)
    float* Lacc = (float*)(ws + (34ull << 20));     // 160 KiB (32 x 1280 f32)
    bf16* qb    = (bf16*)(ws + (40ull << 20));      // 8 MiB
    bf16* kb    = (bf16*)(ws + (48ull << 20));      // 8 MiB
    bf16* vt    = (bf16*)(ws + (56ull << 20));      // 8 MiB

    cvt_all<<<8192, 256, 0, stream>>>(x, wq, wk, wv, wo, xb, wqkvb, wob);
    gemm_qkv_rope<<<dim3(24, 32), 256, 0, stream>>>(xb, wqkvb, qb, kb, vt);

    hipMemsetAsync(Oacc, 0, (10ull << 20) + 32 * 1280 * sizeof(float), stream);
    attn_kernel<<<dim3(24, 32), 256, 0, stream>>>(qb, kb, vt, Oacc, Lacc, conc);
    attn_finalize<<<2560, 256, 0, stream>>>(Oacc, Lacc, conc);

    gemm_bt<<<dim3(8, 32), 256, 0, stream>>>(conc, wob, out, 4096, 1024, 1024);
}

// Round 9
// 188.075 us; speedup vs baseline: 1.0847x; 1.0847x over previous
//
#include <hip/hip_runtime.h>
#include <hip/hip_bf16.h>

typedef __hip_bfloat16 bf16;
typedef __attribute__((ext_vector_type(8))) short bf16x8;
typedef __attribute__((ext_vector_type(4))) float f32x4;

#define T_SEQ 2048
#define NHEADS 16
#define DK 64
#define DMODEL 1024

__device__ inline void load_lds16(const void* g, void* l) {
    __builtin_amdgcn_global_load_lds((const __attribute__((address_space(1))) void*)g,
                                     (__attribute__((address_space(3))) void*)l, 16, 0, 0);
}

// ---------------- fp32 -> bf16 convert: x + all four weights, one launch ----
__global__ void cvt_all(const float* __restrict__ x,  const float* __restrict__ wq,
                        const float* __restrict__ wk, const float* __restrict__ wv,
                        const float* __restrict__ wo, bf16* __restrict__ xb,
                        bf16* __restrict__ wqkvb, bf16* __restrict__ wob) {
    int i = blockIdx.x * blockDim.x + threadIdx.x;   // 0 .. 2M-1 (float4 units)
    const float* src; bf16* dst; int off;
    if (i < (1 << 20)) { src = x; dst = xb; off = i; }
    else {
        int j = i - (1 << 20);
        int seg = j >> 18; off = j & ((1 << 18) - 1);
        src = (seg == 0) ? wq : (seg == 1) ? wk : (seg == 2) ? wv : wo;
        dst = (seg < 3) ? (wqkvb + ((size_t)seg << 20)) : wob;
    }
    float4 f = ((const float4*)src)[off];
    ushort4 o;
    o.x = __bfloat16_as_ushort(__float2bfloat16(f.x));
    o.y = __bfloat16_as_ushort(__float2bfloat16(f.y));
    o.z = __bfloat16_as_ushort(__float2bfloat16(f.z));
    o.w = __bfloat16_as_ushort(__float2bfloat16(f.w));
    ((ushort4*)dst)[off] = o;
}

// ---------------- GEMM1: qkv = x * Wqkv^T, fused RoPE + head split ----------
// v16 structure (BK=64, blk^(row&7) swizzle) — unchanged.
__global__ __launch_bounds__(256, 4) void gemm_qkv_rope(const bf16* __restrict__ A,
                                                        const bf16* __restrict__ B,
                                                        bf16* __restrict__ qb,
                                                        bf16* __restrict__ kb,
                                                        bf16* __restrict__ vt) {
    const int K = 1024;
    __shared__ bf16 As[128 * 64];
    __shared__ bf16 Bs[128 * 64];
    const int tid  = threadIdx.x;
    const int lane = tid & 63;
    const int wave = tid >> 6;
    const int l16  = lane & 15;
    const int quad = lane >> 4;
    const int wy = wave >> 1, wx = wave & 1;
    const int brow = blockIdx.y * 128;
    const int bcol = blockIdx.x * 128;
    const int sw0 = (quad ^ (l16 & 7)) * 8;
    const int sw1 = ((4 + quad) ^ (l16 & 7)) * 8;

    f32x4 acc[4][4] = {};

    for (int k0 = 0; k0 < K; k0 += 64) {
#pragma unroll
        for (int i = 0; i < 4; ++i) {
            int j   = tid + 256 * i;                  // 0..1023
            int row = j >> 3;
            int blk = (j & 7) ^ (row & 7);            // pre-swizzled source blk
            load_lds16(A + (size_t)(brow + row) * K + k0 + blk * 8, (char*)As + j * 16);
            load_lds16(B + (size_t)(bcol + row) * K + k0 + blk * 8, (char*)Bs + j * 16);
        }
        __syncthreads();
#pragma unroll
        for (int ks = 0; ks < 2; ++ks) {
            const int sw = ks ? sw1 : sw0;
            bf16x8 af[4], bq[4];
#pragma unroll
            for (int i = 0; i < 4; ++i)
                af[i] = *(const bf16x8*)(As + (wy * 64 + i * 16 + l16) * 64 + sw);
#pragma unroll
            for (int j = 0; j < 4; ++j)
                bq[j] = *(const bf16x8*)(Bs + (wx * 64 + j * 16 + l16) * 64 + sw);
#pragma unroll
            for (int i = 0; i < 4; ++i)
#pragma unroll
                for (int j = 0; j < 4; ++j)
                    acc[i][j] = __builtin_amdgcn_mfma_f32_16x16x32_bf16(af[i], bq[j], acc[i][j], 0, 0, 0);
        }
        __syncthreads();
    }
    const int seg = bcol >> 10;                       // uniform per block
    const int hh  = ((bcol & 1023) >> 6) + wx;        // head index
    if (seg < 2) {
        bf16* dst = seg ? kb : qb;
        // q pre-scaled so attn computes p = exp2(q'.k) directly
        const float osc = seg ? 1.0f : 0.18033688011112042f;  // log2(e)/8
#pragma unroll
        for (int j = 0; j < 4; ++j) {
            const int d = j * 16 + l16;               // dk within head
            const float inv = exp2f(-0.31143075889f * (float)(d >> 1));  // 1000^(-i/32)
#pragma unroll
            for (int i = 0; i < 4; ++i)
#pragma unroll
                for (int r = 0; r < 4; ++r) {
                    int row = brow + wy * 64 + i * 16 + quad * 4 + r;
                    int t = row & (T_SEQ - 1), bi = row >> 11;
                    float s, c;
                    __sincosf((float)t * inv, &s, &c);
                    float v = acc[i][j][r];
                    float p = __shfl_xor(v, 1);
                    float res = (l16 & 1) ? fmaf(p, s, v * c) : fmaf(-p, s, v * c);
                    dst[((size_t)(bi * NHEADS + hh) * T_SEQ + t) * DK + d] =
                        __float2bfloat16(res * osc);
                }
        }
    } else {
#pragma unroll
        for (int j = 0; j < 4; ++j) {
            const int d = j * 16 + l16;
#pragma unroll
            for (int i = 0; i < 4; ++i)
#pragma unroll
                for (int r = 0; r < 4; ++r) {
                    int row = brow + wy * 64 + i * 16 + quad * 4 + r;
                    int t = row & (T_SEQ - 1), bi = row >> 11;
                    vt[((size_t)(bi * NHEADS + hh) * DK + d) * T_SEQ + t] =
                        __float2bfloat16(acc[i][j][r]);
                }
        }
    }
}

// ---------------- GEMM: C[M,N] = A[M,K] * B[N,K]^T (fp32 out) ----------------
// v18: BN 128 -> 64 so grid = (N/64, M/128) = 512 blocks = 2 blocks/CU
// (was 256 = 1/CU: zero cross-block overlap to hide the DMA drain). LDS
// 24 KB/block. Per-wave tile 64x32 (acc[4][2]); same swizzle/staging scheme.
__global__ __launch_bounds__(256, 4) void gemm_bt(const bf16* __restrict__ A,
                                                  const bf16* __restrict__ B,
                                                  float* __restrict__ C,
                                                  int M, int N, int K) {
    __shared__ bf16 As[128 * 64];
    __shared__ bf16 Bs[64 * 64];
    const int tid  = threadIdx.x;
    const int lane = tid & 63;
    const int wave = tid >> 6;
    const int l16  = lane & 15;
    const int quad = lane >> 4;
    const int wy = wave >> 1, wx = wave & 1;
    const int brow = blockIdx.y * 128;
    const int bcol = blockIdx.x * 64;
    const int sw0 = (quad ^ (l16 & 7)) * 8;
    const int sw1 = ((4 + quad) ^ (l16 & 7)) * 8;

    f32x4 acc[4][2] = {};

    for (int k0 = 0; k0 < K; k0 += 64) {
#pragma unroll
        for (int i = 0; i < 4; ++i) {                 // A: 128x64 = 1024 x 16B
            int j   = tid + 256 * i;
            int row = j >> 3;
            int blk = (j & 7) ^ (row & 7);
            load_lds16(A + (size_t)(brow + row) * K + k0 + blk * 8, (char*)As + j * 16);
        }
#pragma unroll
        for (int i = 0; i < 2; ++i) {                 // B: 64x64 = 512 x 16B
            int j   = tid + 256 * i;
            int row = j >> 3;
            int blk = (j & 7) ^ (row & 7);
            load_lds16(B + (size_t)(bcol + row) * K + k0 + blk * 8, (char*)Bs + j * 16);
        }
        __syncthreads();
#pragma unroll
        for (int ks = 0; ks < 2; ++ks) {
            const int sw = ks ? sw1 : sw0;
            bf16x8 af[4], bq[2];
#pragma unroll
            for (int i = 0; i < 4; ++i)
                af[i] = *(const bf16x8*)(As + (wy * 64 + i * 16 + l16) * 64 + sw);
#pragma unroll
            for (int j = 0; j < 2; ++j)
                bq[j] = *(const bf16x8*)(Bs + (wx * 32 + j * 16 + l16) * 64 + sw);
#pragma unroll
            for (int i = 0; i < 4; ++i)
#pragma unroll
                for (int j = 0; j < 2; ++j)
                    acc[i][j] = __builtin_amdgcn_mfma_f32_16x16x32_bf16(af[i], bq[j], acc[i][j], 0, 0, 0);
        }
        __syncthreads();
    }
#pragma unroll
    for (int i = 0; i < 4; ++i)
#pragma unroll
        for (int j = 0; j < 2; ++j)
#pragma unroll
            for (int r = 0; r < 4; ++r) {
                int row = brow + wy * 64 + i * 16 + quad * 4 + r;
                int col = bcol + wx * 32 + j * 16 + l16;
                C[(size_t)row * N + col] = acc[i][j][r];
            }
}

// ---------------- flash attention v12/v16 schedule (REVERTED from v17) ------
// v17's 12-iter balanced parcels regressed (-18 us): +48 MB HBM (atomic RMW
// writers 2->3, region 1024->1280 rows) swamped the 4-iter makespan gain.
// The v16 schedule is near the atomic-cost/makespan optimum for this split.
__constant__ unsigned char c_sched[24] = {
    28, 61, 57, 58, 24, 53, 49, 20,
    62, 54, 50, 41, 42, 16, 45, 46,
     0,  4,  8, 12, 33, 37, 34, 38};

__global__ __launch_bounds__(256, 4) void attn_kernel(const bf16* __restrict__ qb,
                                                      const bf16* __restrict__ kb,
                                                      const bf16* __restrict__ vt,
                                                      float* __restrict__ Oacc,
                                                      float* __restrict__ Lacc,
                                                      bf16* __restrict__ conc) {
    __shared__ bf16 Ks[2][64 * 64];                // 2 x 8 KB
    __shared__ bf16 Vs[2][64 * 64];                // 2 x 8 KB
    __shared__ bf16 Pl[4][16 * 64];                // 8 KB (per-wave, shared g0/g1)
    const int bh = blockIdx.y;
    const int b = bh >> 4, h = bh & 15;

    const int e    = c_sched[blockIdx.x];
    const int tile = e >> 2, mode = e & 3;
    const int it0  = (mode == 2) ? tile + 1 : 0;
    const int it1  = (mode == 1) ? tile : 2 * tile + 1;
    const bool partial = (mode != 0);
    const int qbase = tile << 7;                   // 128 queries per tile

    const int tid = threadIdx.x;
    const int lane = tid & 63, wave = tid >> 6;
    const int l16 = lane & 15, quad = lane >> 4;
    const int qr0 = qbase + wave * 16;             // group0 query rows
    const int qr1 = qr0 + 64;                      // group1 query rows

    const bf16* Qp = qb + (size_t)bh * T_SEQ * DK;
    const bf16* Kp = kb + (size_t)bh * T_SEQ * DK;
    const bf16* Vp = vt + (size_t)bh * DK * T_SEQ;
    char* Pw = (char*)&Pl[wave][0];

    // ones B-fragment for the l row-sum MFMA
    const short one_bits = 0x3F80;
    const bf16x8 ones = {one_bits, one_bits, one_bits, one_bits,
                         one_bits, one_bits, one_bits, one_bits};

    // Q as B-operand: n = query = l16, k = dk = quad*8+j (+32 per kstep)
    bf16x8 qf[2][2];
#pragma unroll
    for (int s = 0; s < 2; ++s) {
        qf[0][s] = *(const bf16x8*)(Qp + (size_t)(qr0 + l16) * DK + s * 32 + quad * 8);
        qf[1][s] = *(const bf16x8*)(Qp + (size_t)(qr1 + l16) * DK + s * 32 + quad * 8);
    }

    // stage row-major 64x64 tile with XOR-swizzled 16B col-blocks
    auto stage = [&](int bb, int k0) {
        int j = tid;
#pragma unroll
        for (int i = 0; i < 2; ++i, j += 256) {
            int row = j >> 3, cbl = (j & 7) ^ ((j >> 3) & 7);
            load_lds16(Kp + (size_t)(k0 + row) * DK + cbl * 8, (char*)Ks[bb] + j * 16);
        }
        j = tid;
#pragma unroll
        for (int i = 0; i < 2; ++i, j += 256) {
            int row = j >> 3, cbl = (j & 7) ^ ((j >> 3) & 7);
            load_lds16(Vp + (size_t)row * T_SEQ + k0 + cbl * 8, (char*)Vs[bb] + j * 16);
        }
    };

    f32x4 o0[4] = {}, o1[4] = {};
    f32x4 ol0 = {}, ol1 = {};      // l row-sums (same C-rows as o*[j])
    const int sw0 = (quad ^ (l16 & 7)) * 8;
    const int sw1 = ((4 + quad) ^ (l16 & 7)) * 8;
    // P buffer addressing (bytes): row=l16 (128B), XOR-swizzled 16B blocks
    const int pw_wr_base = l16 * 128 + (quad & 1) * 8;   // + swizzled block
    const int pq = quad >> 1;

    int cur = 0;
    stage(0, it0 * 64);
    for (int it = it0; it <= it1; ++it) {
        __syncthreads();                      // drains DMA for cur + syncs waves
        if (it < it1) stage(cur ^ 1, (it + 1) * 64);

        const int k0 = it * 64;
        const bool skip0 = (k0 > qr0 + 15);             // wave-uniform
        const bool diag0 = (k0 + 63 > qr0) && !skip0;
        const bool diag1 = (k0 + 63 > qr1);             // skip1 never happens

        // S^T = K Q^T over 64 keys; kf fragments shared by both groups
        f32x4 s0[4] = {}, s1[4] = {};
        __builtin_amdgcn_s_setprio(1);
#pragma unroll
        for (int nt = 0; nt < 4; ++nt) {
            bf16x8 kf0 = *(const bf16x8*)(Ks[cur] + (nt * 16 + l16) * 64 + sw0);
            bf16x8 kf1 = *(const bf16x8*)(Ks[cur] + (nt * 16 + l16) * 64 + sw1);
            if (!skip0) {
                s0[nt] = __builtin_amdgcn_mfma_f32_16x16x32_bf16(kf0, qf[0][0], s0[nt], 0, 0, 0);
                s0[nt] = __builtin_amdgcn_mfma_f32_16x16x32_bf16(kf1, qf[0][1], s0[nt], 0, 0, 0);
            }
            s1[nt] = __builtin_amdgcn_mfma_f32_16x16x32_bf16(kf0, qf[1][0], s1[nt], 0, 0, 0);
            s1[nt] = __builtin_amdgcn_mfma_f32_16x16x32_bf16(kf1, qf[1][1], s1[nt], 0, 0, 0);
        }
        __builtin_amdgcn_s_setprio(0);

        // ---- group 0: exp -> P buffer -> PV (+ l-sum MFMA) ----
        if (!skip0) {
#pragma unroll
            for (int nt = 0; nt < 4; ++nt) {
                union { bf16 hv[4]; uint2 u; } pk;
#pragma unroll
                for (int r = 0; r < 4; ++r) {
                    float v = s0[nt][r];
                    if (diag0 && (k0 + nt * 16 + quad * 4 + r > qr0 + l16)) v = -30.0f;
                    pk.hv[r] = __float2bfloat16(exp2f(v));
                }
                *(uint2*)(Pw + pw_wr_base + (((nt * 2 + pq) ^ (l16 & 7)) << 4)) = pk.u;
            }
            __builtin_amdgcn_s_setprio(1);
#pragma unroll
            for (int ks = 0; ks < 2; ++ks) {
                bf16x8 pf = *(const bf16x8*)(Pw + l16 * 128 + (((ks * 4 + quad) ^ (l16 & 7)) << 4));
                const int sw = ks ? sw1 : sw0;
                ol0 = __builtin_amdgcn_mfma_f32_16x16x32_bf16(pf, ones, ol0, 0, 0, 0);
#pragma unroll
                for (int j = 0; j < 4; ++j) {
                    bf16x8 vf = *(const bf16x8*)(Vs[cur] + (j * 16 + l16) * 64 + sw);
                    o0[j] = __builtin_amdgcn_mfma_f32_16x16x32_bf16(pf, vf, o0[j], 0, 0, 0);
                }
            }
            __builtin_amdgcn_s_setprio(0);
        }

        // ---- group 1: exp -> P buffer (reused; per-wave DS pipe is in-order,
        // so these writes cannot pass g0's pf reads) -> PV (+ l-sum MFMA) ----
#pragma unroll
        for (int nt = 0; nt < 4; ++nt) {
            union { bf16 hv[4]; uint2 u; } pk;
#pragma unroll
            for (int r = 0; r < 4; ++r) {
                float v = s1[nt][r];
                if (diag1 && (k0 + nt * 16 + quad * 4 + r > qr1 + l16)) v = -30.0f;
                pk.hv[r] = __float2bfloat16(exp2f(v));
            }
            *(uint2*)(Pw + pw_wr_base + (((nt * 2 + pq) ^ (l16 & 7)) << 4)) = pk.u;
        }
        __builtin_amdgcn_s_setprio(1);
#pragma unroll
        for (int ks = 0; ks < 2; ++ks) {
            bf16x8 pf = *(const bf16x8*)(Pw + l16 * 128 + (((ks * 4 + quad) ^ (l16 & 7)) << 4));
            const int sw = ks ? sw1 : sw0;
            ol1 = __builtin_amdgcn_mfma_f32_16x16x32_bf16(pf, ones, ol1, 0, 0, 0);
#pragma unroll
            for (int j = 0; j < 4; ++j) {
                bf16x8 vf = *(const bf16x8*)(Vs[cur] + (j * 16 + l16) * 64 + sw);
                o1[j] = __builtin_amdgcn_mfma_f32_16x16x32_bf16(pf, vf, o1[j], 0, 0, 0);
            }
        }
        __builtin_amdgcn_s_setprio(0);
        cur ^= 1;
    }

    // epilogue: ol*[r] is the full l for query qr + quad*4 + r (no shuffles)
#pragma unroll
    for (int g = 0; g < 2; ++g) {
        const f32x4* op = g ? o1 : o0;
        const f32x4 lv = g ? ol1 : ol0;
        const int qr = g ? qr1 : qr0;
        if (!partial) {
#pragma unroll
            for (int r = 0; r < 4; ++r) {
                float inv_l = 1.0f / lv[r];
                int t = qr + quad * 4 + r;
#pragma unroll
                for (int j = 0; j < 4; ++j)
                    conc[((size_t)b * T_SEQ + t) * DMODEL + h * DK + j * 16 + l16] =
                        __float2bfloat16(op[j][r] * inv_l);
            }
        } else {
#pragma unroll
            for (int r = 0; r < 4; ++r) {
                int q = qr + quad * 4 + r;
                if (l16 == 0)
                    atomicAdd(&Lacc[(size_t)bh * 1024 + q - 1024], lv[r]);
                float* Ob = Oacc + ((size_t)bh * 1024 + q - 1024) * DK;
#pragma unroll
                for (int j = 0; j < 4; ++j)
                    atomicAdd(&Ob[j * 16 + l16], op[j][r]);
            }
        }
    }
}

// ---------------- normalize + concat (only q in [1024, 2048)) ----------------
__global__ void attn_finalize(const float* __restrict__ Oacc, const float* __restrict__ Lacc,
                              bf16* __restrict__ conc) {
    int i4 = blockIdx.x * blockDim.x + threadIdx.x;   // float4 units, 0..512K-1
    if (i4 >= (1 << 19)) return;
    int bhq = i4 >> 4;          // bh*1024 + q1
    int d4  = i4 & 15;
    int bh = bhq >> 10, q1 = bhq & 1023;
    int b = bh >> 4, h = bh & 15;
    int q = 1024 + q1;
    float inv = 1.0f / Lacc[bhq];
    float4 o4 = ((const float4*)Oacc)[i4];
    ushort4 u;
    u.x = __bfloat16_as_ushort(__float2bfloat16(o4.x * inv));
    u.y = __bfloat16_as_ushort(__float2bfloat16(o4.y * inv));
    u.z = __bfloat16_as_ushort(__float2bfloat16(o4.z * inv));
    u.w = __bfloat16_as_ushort(__float2bfloat16(o4.w * inv));
    *(ushort4*)&conc[((size_t)(b * T_SEQ + q)) * DMODEL + h * DK + d4 * 4] = u;
}

extern "C" void kernel_launch(void* const* d_in, const int* in_sizes, int n_in,
                              void* d_out, int out_size, void* d_ws, size_t ws_size,
                              hipStream_t stream) {
    const float* x  = (const float*)d_in[0];
    const float* wq = (const float*)d_in[1];
    const float* wk = (const float*)d_in[2];
    const float* wv = (const float*)d_in[3];
    const float* wo = (const float*)d_in[4];
    float* out = (float*)d_out;

    char* ws = (char*)d_ws;
    bf16* xb    = (bf16*)(ws);                      // 8 MiB  (4096x1024)
    bf16* wqkvb = (bf16*)(ws + (8ull << 20));       // 6 MiB  (3072x1024)
    bf16* wob   = (bf16*)(ws + (14ull << 20));      // 2 MiB  (1024x1024)
    bf16* conc  = (bf16*)(ws + (16ull << 20));      // 8 MiB
    float* Oacc = (float*)(ws + (24ull << 20));     // 8 MiB
    float* Lacc = (float*)(ws + (32ull << 20));     // 128 KiB
    bf16* qb    = (bf16*)(ws + (40ull << 20));      // 8 MiB
    bf16* kb    = (bf16*)(ws + (48ull << 20));      // 8 MiB
    bf16* vt    = (bf16*)(ws + (56ull << 20));      // 8 MiB

    cvt_all<<<8192, 256, 0, stream>>>(x, wq, wk, wv, wo, xb, wqkvb, wob);
    gemm_qkv_rope<<<dim3(24, 32), 256, 0, stream>>>(xb, wqkvb, qb, kb, vt);

    hipMemsetAsync(Oacc, 0, (8ull << 20) + 32 * 1024 * sizeof(float), stream);
    attn_kernel<<<dim3(24, 32), 256, 0, stream>>>(qb, kb, vt, Oacc, Lacc, conc);
    attn_finalize<<<2048, 256, 0, stream>>>(Oacc, Lacc, conc);

    gemm_bt<<<dim3(16, 32), 256, 0, stream>>>(conc, wob, out, 4096, 1024, 1024);
}

// Round 10
// 186.427 us; speedup vs baseline: 1.0943x; 1.0088x over previous
//
#include <hip/hip_runtime.h>
#include <hip/hip_bf16.h>

typedef __hip_bfloat16 bf16;
typedef __attribute__((ext_vector_type(8))) short bf16x8;
typedef __attribute__((ext_vector_type(4))) float f32x4;

#define T_SEQ 2048
#define NHEADS 16
#define DK 64
#define DMODEL 1024

__device__ inline void load_lds16(const void* g, void* l) {
    __builtin_amdgcn_global_load_lds((const __attribute__((address_space(1))) void*)g,
                                     (__attribute__((address_space(3))) void*)l, 16, 0, 0);
}

// ---- fp32 -> bf16 convert (x + weights) + zero-fill of Oacc/Lacc tail ------
// v19: absorbs the hipMemsetAsync dispatch. Blocks cover 2M cvt float4 units
// + 532480 zero float4 units (Oacc 8 MiB + Lacc 128 KiB, contiguous).
__global__ void cvt_all(const float* __restrict__ x,  const float* __restrict__ wq,
                        const float* __restrict__ wk, const float* __restrict__ wv,
                        const float* __restrict__ wo, bf16* __restrict__ xb,
                        bf16* __restrict__ wqkvb, bf16* __restrict__ wob,
                        float4* __restrict__ zacc) {
    int i = blockIdx.x * blockDim.x + threadIdx.x;
    if (i >= (1 << 21)) {                            // zero tail: Oacc+Lacc
        zacc[i - (1 << 21)] = make_float4(0.f, 0.f, 0.f, 0.f);
        return;
    }
    const float* src; bf16* dst; int off;
    if (i < (1 << 20)) { src = x; dst = xb; off = i; }
    else {
        int j = i - (1 << 20);
        int seg = j >> 18; off = j & ((1 << 18) - 1);
        src = (seg == 0) ? wq : (seg == 1) ? wk : (seg == 2) ? wv : wo;
        dst = (seg < 3) ? (wqkvb + ((size_t)seg << 20)) : wob;
    }
    float4 f = ((const float4*)src)[off];
    ushort4 o;
    o.x = __bfloat16_as_ushort(__float2bfloat16(f.x));
    o.y = __bfloat16_as_ushort(__float2bfloat16(f.y));
    o.z = __bfloat16_as_ushort(__float2bfloat16(f.z));
    o.w = __bfloat16_as_ushort(__float2bfloat16(f.w));
    ((ushort4*)dst)[off] = o;
}

// ---------------- GEMM1: qkv = x * Wqkv^T, fused RoPE + head split ----------
// v16 structure (BK=64, blk^(row&7) swizzle) — unchanged.
__global__ __launch_bounds__(256, 4) void gemm_qkv_rope(const bf16* __restrict__ A,
                                                        const bf16* __restrict__ B,
                                                        bf16* __restrict__ qb,
                                                        bf16* __restrict__ kb,
                                                        bf16* __restrict__ vt) {
    const int K = 1024;
    __shared__ bf16 As[128 * 64];
    __shared__ bf16 Bs[128 * 64];
    const int tid  = threadIdx.x;
    const int lane = tid & 63;
    const int wave = tid >> 6;
    const int l16  = lane & 15;
    const int quad = lane >> 4;
    const int wy = wave >> 1, wx = wave & 1;
    const int brow = blockIdx.y * 128;
    const int bcol = blockIdx.x * 128;
    const int sw0 = (quad ^ (l16 & 7)) * 8;
    const int sw1 = ((4 + quad) ^ (l16 & 7)) * 8;

    f32x4 acc[4][4] = {};

    for (int k0 = 0; k0 < K; k0 += 64) {
#pragma unroll
        for (int i = 0; i < 4; ++i) {
            int j   = tid + 256 * i;                  // 0..1023
            int row = j >> 3;
            int blk = (j & 7) ^ (row & 7);            // pre-swizzled source blk
            load_lds16(A + (size_t)(brow + row) * K + k0 + blk * 8, (char*)As + j * 16);
            load_lds16(B + (size_t)(bcol + row) * K + k0 + blk * 8, (char*)Bs + j * 16);
        }
        __syncthreads();
#pragma unroll
        for (int ks = 0; ks < 2; ++ks) {
            const int sw = ks ? sw1 : sw0;
            bf16x8 af[4], bq[4];
#pragma unroll
            for (int i = 0; i < 4; ++i)
                af[i] = *(const bf16x8*)(As + (wy * 64 + i * 16 + l16) * 64 + sw);
#pragma unroll
            for (int j = 0; j < 4; ++j)
                bq[j] = *(const bf16x8*)(Bs + (wx * 64 + j * 16 + l16) * 64 + sw);
#pragma unroll
            for (int i = 0; i < 4; ++i)
#pragma unroll
                for (int j = 0; j < 4; ++j)
                    acc[i][j] = __builtin_amdgcn_mfma_f32_16x16x32_bf16(af[i], bq[j], acc[i][j], 0, 0, 0);
        }
        __syncthreads();
    }
    const int seg = bcol >> 10;                       // uniform per block
    const int hh  = ((bcol & 1023) >> 6) + wx;        // head index
    if (seg < 2) {
        bf16* dst = seg ? kb : qb;
        // q pre-scaled so attn computes p = exp2(q'.k) directly
        const float osc = seg ? 1.0f : 0.18033688011112042f;  // log2(e)/8
#pragma unroll
        for (int j = 0; j < 4; ++j) {
            const int d = j * 16 + l16;               // dk within head
            const float inv = exp2f(-0.31143075889f * (float)(d >> 1));  // 1000^(-i/32)
#pragma unroll
            for (int i = 0; i < 4; ++i)
#pragma unroll
                for (int r = 0; r < 4; ++r) {
                    int row = brow + wy * 64 + i * 16 + quad * 4 + r;
                    int t = row & (T_SEQ - 1), bi = row >> 11;
                    float s, c;
                    __sincosf((float)t * inv, &s, &c);
                    float v = acc[i][j][r];
                    float p = __shfl_xor(v, 1);
                    float res = (l16 & 1) ? fmaf(p, s, v * c) : fmaf(-p, s, v * c);
                    dst[((size_t)(bi * NHEADS + hh) * T_SEQ + t) * DK + d] =
                        __float2bfloat16(res * osc);
                }
        }
    } else {
#pragma unroll
        for (int j = 0; j < 4; ++j) {
            const int d = j * 16 + l16;
#pragma unroll
            for (int i = 0; i < 4; ++i)
#pragma unroll
                for (int r = 0; r < 4; ++r) {
                    int row = brow + wy * 64 + i * 16 + quad * 4 + r;
                    int t = row & (T_SEQ - 1), bi = row >> 11;
                    vt[((size_t)(bi * NHEADS + hh) * DK + d) * T_SEQ + t] =
                        __float2bfloat16(acc[i][j][r]);
                }
        }
    }
}

// ---------------- GEMM: C[M,N] = A[M,K] * B[N,K]^T (fp32 out) ----------------
// v16 (BN=128) — REVERTED from v18's BN=64 (regressed 5.4 us: +50% staging
// issue volume and 2x A re-fetch outweighed the 2-blocks/CU overlap gain).
__global__ __launch_bounds__(256, 4) void gemm_bt(const bf16* __restrict__ A,
                                                  const bf16* __restrict__ B,
                                                  float* __restrict__ C,
                                                  int M, int N, int K) {
    __shared__ bf16 As[128 * 64];
    __shared__ bf16 Bs[128 * 64];
    const int tid  = threadIdx.x;
    const int lane = tid & 63;
    const int wave = tid >> 6;
    const int l16  = lane & 15;
    const int quad = lane >> 4;
    const int wy = wave >> 1, wx = wave & 1;
    const int brow = blockIdx.y * 128;
    const int bcol = blockIdx.x * 128;
    const int sw0 = (quad ^ (l16 & 7)) * 8;
    const int sw1 = ((4 + quad) ^ (l16 & 7)) * 8;

    f32x4 acc[4][4] = {};

    for (int k0 = 0; k0 < K; k0 += 64) {
#pragma unroll
        for (int i = 0; i < 4; ++i) {
            int j   = tid + 256 * i;
            int row = j >> 3;
            int blk = (j & 7) ^ (row & 7);
            load_lds16(A + (size_t)(brow + row) * K + k0 + blk * 8, (char*)As + j * 16);
            load_lds16(B + (size_t)(bcol + row) * K + k0 + blk * 8, (char*)Bs + j * 16);
        }
        __syncthreads();
#pragma unroll
        for (int ks = 0; ks < 2; ++ks) {
            const int sw = ks ? sw1 : sw0;
            bf16x8 af[4], bq[4];
#pragma unroll
            for (int i = 0; i < 4; ++i)
                af[i] = *(const bf16x8*)(As + (wy * 64 + i * 16 + l16) * 64 + sw);
#pragma unroll
            for (int j = 0; j < 4; ++j)
                bq[j] = *(const bf16x8*)(Bs + (wx * 64 + j * 16 + l16) * 64 + sw);
#pragma unroll
            for (int i = 0; i < 4; ++i)
#pragma unroll
                for (int j = 0; j < 4; ++j)
                    acc[i][j] = __builtin_amdgcn_mfma_f32_16x16x32_bf16(af[i], bq[j], acc[i][j], 0, 0, 0);
        }
        __syncthreads();
    }
#pragma unroll
    for (int i = 0; i < 4; ++i)
#pragma unroll
        for (int j = 0; j < 4; ++j)
#pragma unroll
            for (int r = 0; r < 4; ++r) {
                int row = brow + wy * 64 + i * 16 + quad * 4 + r;
                int col = bcol + wx * 64 + j * 16 + l16;
                C[(size_t)row * N + col] = acc[i][j][r];
            }
}

// ---------------- flash attention v12/v16 schedule ---------------------------
__constant__ unsigned char c_sched[24] = {
    28, 61, 57, 58, 24, 53, 49, 20,
    62, 54, 50, 41, 42, 16, 45, 46,
     0,  4,  8, 12, 33, 37, 34, 38};

__global__ __launch_bounds__(256, 4) void attn_kernel(const bf16* __restrict__ qb,
                                                      const bf16* __restrict__ kb,
                                                      const bf16* __restrict__ vt,
                                                      float* __restrict__ Oacc,
                                                      float* __restrict__ Lacc,
                                                      bf16* __restrict__ conc) {
    __shared__ bf16 Ks[2][64 * 64];                // 2 x 8 KB
    __shared__ bf16 Vs[2][64 * 64];                // 2 x 8 KB
    __shared__ bf16 Pl[4][16 * 64];                // 8 KB (per-wave, shared g0/g1)
    const int bh = blockIdx.y;
    const int b = bh >> 4, h = bh & 15;

    const int e    = c_sched[blockIdx.x];
    const int tile = e >> 2, mode = e & 3;
    const int it0  = (mode == 2) ? tile + 1 : 0;
    const int it1  = (mode == 1) ? tile : 2 * tile + 1;
    const bool partial = (mode != 0);
    const int qbase = tile << 7;                   // 128 queries per tile

    const int tid = threadIdx.x;
    const int lane = tid & 63, wave = tid >> 6;
    const int l16 = lane & 15, quad = lane >> 4;
    const int qr0 = qbase + wave * 16;             // group0 query rows
    const int qr1 = qr0 + 64;                      // group1 query rows

    const bf16* Qp = qb + (size_t)bh * T_SEQ * DK;
    const bf16* Kp = kb + (size_t)bh * T_SEQ * DK;
    const bf16* Vp = vt + (size_t)bh * DK * T_SEQ;
    char* Pw = (char*)&Pl[wave][0];

    // ones B-fragment for the l row-sum MFMA
    const short one_bits = 0x3F80;
    const bf16x8 ones = {one_bits, one_bits, one_bits, one_bits,
                         one_bits, one_bits, one_bits, one_bits};

    // Q as B-operand: n = query = l16, k = dk = quad*8+j (+32 per kstep)
    bf16x8 qf[2][2];
#pragma unroll
    for (int s = 0; s < 2; ++s) {
        qf[0][s] = *(const bf16x8*)(Qp + (size_t)(qr0 + l16) * DK + s * 32 + quad * 8);
        qf[1][s] = *(const bf16x8*)(Qp + (size_t)(qr1 + l16) * DK + s * 32 + quad * 8);
    }

    // stage row-major 64x64 tile with XOR-swizzled 16B col-blocks
    auto stage = [&](int bb, int k0) {
        int j = tid;
#pragma unroll
        for (int i = 0; i < 2; ++i, j += 256) {
            int row = j >> 3, cbl = (j & 7) ^ ((j >> 3) & 7);
            load_lds16(Kp + (size_t)(k0 + row) * DK + cbl * 8, (char*)Ks[bb] + j * 16);
        }
        j = tid;
#pragma unroll
        for (int i = 0; i < 2; ++i, j += 256) {
            int row = j >> 3, cbl = (j & 7) ^ ((j >> 3) & 7);
            load_lds16(Vp + (size_t)row * T_SEQ + k0 + cbl * 8, (char*)Vs[bb] + j * 16);
        }
    };

    f32x4 o0[4] = {}, o1[4] = {};
    f32x4 ol0 = {}, ol1 = {};      // l row-sums (same C-rows as o*[j])
    const int sw0 = (quad ^ (l16 & 7)) * 8;
    const int sw1 = ((4 + quad) ^ (l16 & 7)) * 8;
    // P buffer addressing (bytes): row=l16 (128B), XOR-swizzled 16B blocks
    const int pw_wr_base = l16 * 128 + (quad & 1) * 8;   // + swizzled block
    const int pq = quad >> 1;

    int cur = 0;
    stage(0, it0 * 64);
    for (int it = it0; it <= it1; ++it) {
        __syncthreads();                      // drains DMA for cur + syncs waves
        if (it < it1) stage(cur ^ 1, (it + 1) * 64);

        const int k0 = it * 64;
        const bool skip0 = (k0 > qr0 + 15);             // wave-uniform
        const bool diag0 = (k0 + 63 > qr0) && !skip0;
        const bool diag1 = (k0 + 63 > qr1);             // skip1 never happens

        // S^T = K Q^T over 64 keys; kf fragments shared by both groups
        f32x4 s0[4] = {}, s1[4] = {};
        __builtin_amdgcn_s_setprio(1);
#pragma unroll
        for (int nt = 0; nt < 4; ++nt) {
            bf16x8 kf0 = *(const bf16x8*)(Ks[cur] + (nt * 16 + l16) * 64 + sw0);
            bf16x8 kf1 = *(const bf16x8*)(Ks[cur] + (nt * 16 + l16) * 64 + sw1);
            if (!skip0) {
                s0[nt] = __builtin_amdgcn_mfma_f32_16x16x32_bf16(kf0, qf[0][0], s0[nt], 0, 0, 0);
                s0[nt] = __builtin_amdgcn_mfma_f32_16x16x32_bf16(kf1, qf[0][1], s0[nt], 0, 0, 0);
            }
            s1[nt] = __builtin_amdgcn_mfma_f32_16x16x32_bf16(kf0, qf[1][0], s1[nt], 0, 0, 0);
            s1[nt] = __builtin_amdgcn_mfma_f32_16x16x32_bf16(kf1, qf[1][1], s1[nt], 0, 0, 0);
        }
        __builtin_amdgcn_s_setprio(0);

        // ---- group 0: exp -> P buffer -> PV (+ l-sum MFMA) ----
        if (!skip0) {
#pragma unroll
            for (int nt = 0; nt < 4; ++nt) {
                union { bf16 hv[4]; uint2 u; } pk;
#pragma unroll
                for (int r = 0; r < 4; ++r) {
                    float v = s0[nt][r];
                    if (diag0 && (k0 + nt * 16 + quad * 4 + r > qr0 + l16)) v = -30.0f;
                    pk.hv[r] = __float2bfloat16(exp2f(v));
                }
                *(uint2*)(Pw + pw_wr_base + (((nt * 2 + pq) ^ (l16 & 7)) << 4)) = pk.u;
            }
            __builtin_amdgcn_s_setprio(1);
#pragma unroll
            for (int ks = 0; ks < 2; ++ks) {
                bf16x8 pf = *(const bf16x8*)(Pw + l16 * 128 + (((ks * 4 + quad) ^ (l16 & 7)) << 4));
                const int sw = ks ? sw1 : sw0;
                ol0 = __builtin_amdgcn_mfma_f32_16x16x32_bf16(pf, ones, ol0, 0, 0, 0);
#pragma unroll
                for (int j = 0; j < 4; ++j) {
                    bf16x8 vf = *(const bf16x8*)(Vs[cur] + (j * 16 + l16) * 64 + sw);
                    o0[j] = __builtin_amdgcn_mfma_f32_16x16x32_bf16(pf, vf, o0[j], 0, 0, 0);
                }
            }
            __builtin_amdgcn_s_setprio(0);
        }

        // ---- group 1: exp -> P buffer (reused; per-wave DS pipe is in-order,
        // so these writes cannot pass g0's pf reads) -> PV (+ l-sum MFMA) ----
#pragma unroll
        for (int nt = 0; nt < 4; ++nt) {
            union { bf16 hv[4]; uint2 u; } pk;
#pragma unroll
            for (int r = 0; r < 4; ++r) {
                float v = s1[nt][r];
                if (diag1 && (k0 + nt * 16 + quad * 4 + r > qr1 + l16)) v = -30.0f;
                pk.hv[r] = __float2bfloat16(exp2f(v));
            }
            *(uint2*)(Pw + pw_wr_base + (((nt * 2 + pq) ^ (l16 & 7)) << 4)) = pk.u;
        }
        __builtin_amdgcn_s_setprio(1);
#pragma unroll
        for (int ks = 0; ks < 2; ++ks) {
            bf16x8 pf = *(const bf16x8*)(Pw + l16 * 128 + (((ks * 4 + quad) ^ (l16 & 7)) << 4));
            const int sw = ks ? sw1 : sw0;
            ol1 = __builtin_amdgcn_mfma_f32_16x16x32_bf16(pf, ones, ol1, 0, 0, 0);
#pragma unroll
            for (int j = 0; j < 4; ++j) {
                bf16x8 vf = *(const bf16x8*)(Vs[cur] + (j * 16 + l16) * 64 + sw);
                o1[j] = __builtin_amdgcn_mfma_f32_16x16x32_bf16(pf, vf, o1[j], 0, 0, 0);
            }
        }
        __builtin_amdgcn_s_setprio(0);
        cur ^= 1;
    }

    // epilogue: ol*[r] is the full l for query qr + quad*4 + r (no shuffles)
#pragma unroll
    for (int g = 0; g < 2; ++g) {
        const f32x4* op = g ? o1 : o0;
        const f32x4 lv = g ? ol1 : ol0;
        const int qr = g ? qr1 : qr0;
        if (!partial) {
#pragma unroll
            for (int r = 0; r < 4; ++r) {
                float inv_l = 1.0f / lv[r];
                int t = qr + quad * 4 + r;
#pragma unroll
                for (int j = 0; j < 4; ++j)
                    conc[((size_t)b * T_SEQ + t) * DMODEL + h * DK + j * 16 + l16] =
                        __float2bfloat16(op[j][r] * inv_l);
            }
        } else {
#pragma unroll
            for (int r = 0; r < 4; ++r) {
                int q = qr + quad * 4 + r;
                if (l16 == 0)
                    atomicAdd(&Lacc[(size_t)bh * 1024 + q - 1024], lv[r]);
                float* Ob = Oacc + ((size_t)bh * 1024 + q - 1024) * DK;
#pragma unroll
                for (int j = 0; j < 4; ++j)
                    atomicAdd(&Ob[j * 16 + l16], op[j][r]);
            }
        }
    }
}

// ---------------- normalize + concat (only q in [1024, 2048)) ----------------
__global__ void attn_finalize(const float* __restrict__ Oacc, const float* __restrict__ Lacc,
                              bf16* __restrict__ conc) {
    int i4 = blockIdx.x * blockDim.x + threadIdx.x;   // float4 units, 0..512K-1
    if (i4 >= (1 << 19)) return;
    int bhq = i4 >> 4;          // bh*1024 + q1
    int d4  = i4 & 15;
    int bh = bhq >> 10, q1 = bhq & 1023;
    int b = bh >> 4, h = bh & 15;
    int q = 1024 + q1;
    float inv = 1.0f / Lacc[bhq];
    float4 o4 = ((const float4*)Oacc)[i4];
    ushort4 u;
    u.x = __bfloat16_as_ushort(__float2bfloat16(o4.x * inv));
    u.y = __bfloat16_as_ushort(__float2bfloat16(o4.y * inv));
    u.z = __bfloat16_as_ushort(__float2bfloat16(o4.z * inv));
    u.w = __bfloat16_as_ushort(__float2bfloat16(o4.w * inv));
    *(ushort4*)&conc[((size_t)(b * T_SEQ + q)) * DMODEL + h * DK + d4 * 4] = u;
}

extern "C" void kernel_launch(void* const* d_in, const int* in_sizes, int n_in,
                              void* d_out, int out_size, void* d_ws, size_t ws_size,
                              hipStream_t stream) {
    const float* x  = (const float*)d_in[0];
    const float* wq = (const float*)d_in[1];
    const float* wk = (const float*)d_in[2];
    const float* wv = (const float*)d_in[3];
    const float* wo = (const float*)d_in[4];
    float* out = (float*)d_out;

    char* ws = (char*)d_ws;
    bf16* xb    = (bf16*)(ws);                      // 8 MiB  (4096x1024)
    bf16* wqkvb = (bf16*)(ws + (8ull << 20));       // 6 MiB  (3072x1024)
    bf16* wob   = (bf16*)(ws + (14ull << 20));      // 2 MiB  (1024x1024)
    bf16* conc  = (bf16*)(ws + (16ull << 20));      // 8 MiB
    float* Oacc = (float*)(ws + (24ull << 20));     // 8 MiB
    float* Lacc = (float*)(ws + (32ull << 20));     // 128 KiB (contiguous after Oacc)
    bf16* qb    = (bf16*)(ws + (40ull << 20));      // 8 MiB
    bf16* kb    = (bf16*)(ws + (48ull << 20));      // 8 MiB
    bf16* vt    = (bf16*)(ws + (56ull << 20));      // 8 MiB

    // 8192 cvt blocks + 2080 zero blocks (Oacc 8 MiB + Lacc 128 KiB)
    cvt_all<<<10272, 256, 0, stream>>>(x, wq, wk, wv, wo, xb, wqkvb, wob,
                                       (float4*)Oacc);
    gemm_qkv_rope<<<dim3(24, 32), 256, 0, stream>>>(xb, wqkvb, qb, kb, vt);

    attn_kernel<<<dim3(24, 32), 256, 0, stream>>>(qb, kb, vt, Oacc, Lacc, conc);
    attn_finalize<<<2048, 256, 0, stream>>>(Oacc, Lacc, conc);

    gemm_bt<<<dim3(8, 32), 256, 0, stream>>>(conc, wob, out, 4096, 1024, 1024);
}

// Round 11
// 180.999 us; speedup vs baseline: 1.1271x; 1.0300x over previous
//
#include <hip/hip_runtime.h>
#include <hip/hip_bf16.h>

typedef __hip_bfloat16 bf16;
typedef __attribute__((ext_vector_type(8))) short bf16x8;
typedef __attribute__((ext_vector_type(4))) float f32x4;

#define T_SEQ 2048
#define NHEADS 16
#define DK 64
#define DMODEL 1024

__device__ inline void load_lds16(const void* g, void* l) {
    __builtin_amdgcn_global_load_lds((const __attribute__((address_space(1))) void*)g,
                                     (__attribute__((address_space(3))) void*)l, 16, 0, 0);
}

// ---- fp32 -> bf16 convert (x + weights) + zero-fill of Oacc/Lacc tail ------
__global__ void cvt_all(const float* __restrict__ x,  const float* __restrict__ wq,
                        const float* __restrict__ wk, const float* __restrict__ wv,
                        const float* __restrict__ wo, bf16* __restrict__ xb,
                        bf16* __restrict__ wqkvb, bf16* __restrict__ wob,
                        float4* __restrict__ zacc) {
    int i = blockIdx.x * blockDim.x + threadIdx.x;
    if (i >= (1 << 21)) {                            // zero tail: Oacc+Lacc
        zacc[i - (1 << 21)] = make_float4(0.f, 0.f, 0.f, 0.f);
        return;
    }
    const float* src; bf16* dst; int off;
    if (i < (1 << 20)) { src = x; dst = xb; off = i; }
    else {
        int j = i - (1 << 20);
        int seg = j >> 18; off = j & ((1 << 18) - 1);
        src = (seg == 0) ? wq : (seg == 1) ? wk : (seg == 2) ? wv : wo;
        dst = (seg < 3) ? (wqkvb + ((size_t)seg << 20)) : wob;
    }
    float4 f = ((const float4*)src)[off];
    ushort4 o;
    o.x = __bfloat16_as_ushort(__float2bfloat16(f.x));
    o.y = __bfloat16_as_ushort(__float2bfloat16(f.y));
    o.z = __bfloat16_as_ushort(__float2bfloat16(f.z));
    o.w = __bfloat16_as_ushort(__float2bfloat16(f.w));
    ((ushort4*)dst)[off] = o;
}

// ---------------- GEMM1: qkv = x * Wqkv^T, fused RoPE + head split ----------
// v20: SWAPPED MFMA operands for all blocks (mfma(bq, af) -> C' row = W-dim,
// col = x-row-dim; mapping HW-verified by v14's passing seg-2 path). Each
// lane now owns 4 CONSECUTIVE d at one t:
//   - RoPE pair (2i,2i+1) is register-local (r0/r1, r2/r3): 64 shfl_xor -> 0
//   - angle shared within a pair: 64 sincos/lane -> 32
//   - q/k stores: 64x2B scalar -> 16x8B vectorized
//   - v stores coalesced on t (v14-verified path)
// K-loop (BK=64, blk^(row&7) swizzle) unchanged.
__global__ __launch_bounds__(256, 4) void gemm_qkv_rope(const bf16* __restrict__ A,
                                                        const bf16* __restrict__ B,
                                                        bf16* __restrict__ qb,
                                                        bf16* __restrict__ kb,
                                                        bf16* __restrict__ vt) {
    const int K = 1024;
    __shared__ bf16 As[128 * 64];
    __shared__ bf16 Bs[128 * 64];
    const int tid  = threadIdx.x;
    const int lane = tid & 63;
    const int wave = tid >> 6;
    const int l16  = lane & 15;
    const int quad = lane >> 4;
    const int wy = wave >> 1, wx = wave & 1;
    const int brow = blockIdx.y * 128;
    const int bcol = blockIdx.x * 128;
    const int sw0 = (quad ^ (l16 & 7)) * 8;
    const int sw1 = ((4 + quad) ^ (l16 & 7)) * 8;

    f32x4 acc[4][4] = {};

    for (int k0 = 0; k0 < K; k0 += 64) {
#pragma unroll
        for (int i = 0; i < 4; ++i) {
            int j   = tid + 256 * i;                  // 0..1023
            int row = j >> 3;
            int blk = (j & 7) ^ (row & 7);            // pre-swizzled source blk
            load_lds16(A + (size_t)(brow + row) * K + k0 + blk * 8, (char*)As + j * 16);
            load_lds16(B + (size_t)(bcol + row) * K + k0 + blk * 8, (char*)Bs + j * 16);
        }
        __syncthreads();
#pragma unroll
        for (int ks = 0; ks < 2; ++ks) {
            const int sw = ks ? sw1 : sw0;
            bf16x8 af[4], bq[4];
#pragma unroll
            for (int i = 0; i < 4; ++i)
                af[i] = *(const bf16x8*)(As + (wy * 64 + i * 16 + l16) * 64 + sw);
#pragma unroll
            for (int j = 0; j < 4; ++j)
                bq[j] = *(const bf16x8*)(Bs + (wx * 64 + j * 16 + l16) * 64 + sw);
#pragma unroll
            for (int i = 0; i < 4; ++i)
#pragma unroll
                for (int j = 0; j < 4; ++j)
                    acc[i][j] = __builtin_amdgcn_mfma_f32_16x16x32_bf16(bq[j], af[i], acc[i][j], 0, 0, 0);
        }
        __syncthreads();
    }
    const int seg = bcol >> 10;                       // uniform per block
    const int hh  = ((bcol & 1023) >> 6) + wx;        // head index
    if (seg < 2) {
        bf16* dst = seg ? kb : qb;
        // q pre-scaled so attn computes p = exp2(q'.k) directly
        const float osc = seg ? 1.0f : 0.18033688011112042f;  // log2(e)/8
#pragma unroll
        for (int i = 0; i < 4; ++i) {
            int trow = brow + wy * 64 + i * 16 + l16;
            int t = trow & (T_SEQ - 1), bi = trow >> 11;
            float tf = (float)t;
            bf16* base = dst + ((size_t)(bi * NHEADS + hh) * T_SEQ + t) * DK;
#pragma unroll
            for (int j = 0; j < 4; ++j) {
                ushort4 u;
#pragma unroll
                for (int p = 0; p < 2; ++p) {
                    // d_pair = j*8 + quad*2 + p ; inv = 1000^(-d_pair/32)
                    const float inv = exp2f(-0.31143075889f * (float)(j * 8 + quad * 2 + p));
                    float s, c;
                    __sincosf(tf * inv, &s, &c);
                    float xe = acc[i][j][2 * p], xo = acc[i][j][2 * p + 1];
                    float re = fmaf(-xo, s, xe * c) * osc;
                    float ro = fmaf(xe, s, xo * c) * osc;
                    ((unsigned short*)&u)[2 * p] =
                        __bfloat16_as_ushort(__float2bfloat16(re));
                    ((unsigned short*)&u)[2 * p + 1] =
                        __bfloat16_as_ushort(__float2bfloat16(ro));
                }
                *(ushort4*)(base + j * 16 + quad * 4) = u;   // 4 consecutive d
            }
        }
    } else {
        // v: lane dim (l16 over i) = t -> coalesced vt stores (v14-verified)
#pragma unroll
        for (int j = 0; j < 4; ++j)
#pragma unroll
            for (int i = 0; i < 4; ++i)
#pragma unroll
                for (int r = 0; r < 4; ++r) {
                    int d    = j * 16 + quad * 4 + r;          // dk within head
                    int tcol = brow + wy * 64 + i * 16 + l16;
                    int t = tcol & (T_SEQ - 1), bi = tcol >> 11;
                    vt[((size_t)(bi * NHEADS + hh) * DK + d) * T_SEQ + t] =
                        __float2bfloat16(acc[i][j][r]);
                }
    }
}

// ---------------- GEMM: C[M,N] = A[M,K] * B[N,K]^T (fp32 out) ----------------
// v16 (BN=128) — unchanged.
__global__ __launch_bounds__(256, 4) void gemm_bt(const bf16* __restrict__ A,
                                                  const bf16* __restrict__ B,
                                                  float* __restrict__ C,
                                                  int M, int N, int K) {
    __shared__ bf16 As[128 * 64];
    __shared__ bf16 Bs[128 * 64];
    const int tid  = threadIdx.x;
    const int lane = tid & 63;
    const int wave = tid >> 6;
    const int l16  = lane & 15;
    const int quad = lane >> 4;
    const int wy = wave >> 1, wx = wave & 1;
    const int brow = blockIdx.y * 128;
    const int bcol = blockIdx.x * 128;
    const int sw0 = (quad ^ (l16 & 7)) * 8;
    const int sw1 = ((4 + quad) ^ (l16 & 7)) * 8;

    f32x4 acc[4][4] = {};

    for (int k0 = 0; k0 < K; k0 += 64) {
#pragma unroll
        for (int i = 0; i < 4; ++i) {
            int j   = tid + 256 * i;
            int row = j >> 3;
            int blk = (j & 7) ^ (row & 7);
            load_lds16(A + (size_t)(brow + row) * K + k0 + blk * 8, (char*)As + j * 16);
            load_lds16(B + (size_t)(bcol + row) * K + k0 + blk * 8, (char*)Bs + j * 16);
        }
        __syncthreads();
#pragma unroll
        for (int ks = 0; ks < 2; ++ks) {
            const int sw = ks ? sw1 : sw0;
            bf16x8 af[4], bq[4];
#pragma unroll
            for (int i = 0; i < 4; ++i)
                af[i] = *(const bf16x8*)(As + (wy * 64 + i * 16 + l16) * 64 + sw);
#pragma unroll
            for (int j = 0; j < 4; ++j)
                bq[j] = *(const bf16x8*)(Bs + (wx * 64 + j * 16 + l16) * 64 + sw);
#pragma unroll
            for (int i = 0; i < 4; ++i)
#pragma unroll
                for (int j = 0; j < 4; ++j)
                    acc[i][j] = __builtin_amdgcn_mfma_f32_16x16x32_bf16(af[i], bq[j], acc[i][j], 0, 0, 0);
        }
        __syncthreads();
    }
#pragma unroll
    for (int i = 0; i < 4; ++i)
#pragma unroll
        for (int j = 0; j < 4; ++j)
#pragma unroll
            for (int r = 0; r < 4; ++r) {
                int row = brow + wy * 64 + i * 16 + quad * 4 + r;
                int col = bcol + wx * 64 + j * 16 + l16;
                C[(size_t)row * N + col] = acc[i][j][r];
            }
}

// ---------------- flash attention v12/v16 schedule ---------------------------
__constant__ unsigned char c_sched[24] = {
    28, 61, 57, 58, 24, 53, 49, 20,
    62, 54, 50, 41, 42, 16, 45, 46,
     0,  4,  8, 12, 33, 37, 34, 38};

__global__ __launch_bounds__(256, 4) void attn_kernel(const bf16* __restrict__ qb,
                                                      const bf16* __restrict__ kb,
                                                      const bf16* __restrict__ vt,
                                                      float* __restrict__ Oacc,
                                                      float* __restrict__ Lacc,
                                                      bf16* __restrict__ conc) {
    __shared__ bf16 Ks[2][64 * 64];                // 2 x 8 KB
    __shared__ bf16 Vs[2][64 * 64];                // 2 x 8 KB
    __shared__ bf16 Pl[4][16 * 64];                // 8 KB (per-wave, shared g0/g1)
    const int bh = blockIdx.y;
    const int b = bh >> 4, h = bh & 15;

    const int e    = c_sched[blockIdx.x];
    const int tile = e >> 2, mode = e & 3;
    const int it0  = (mode == 2) ? tile + 1 : 0;
    const int it1  = (mode == 1) ? tile : 2 * tile + 1;
    const bool partial = (mode != 0);
    const int qbase = tile << 7;                   // 128 queries per tile

    const int tid = threadIdx.x;
    const int lane = tid & 63, wave = tid >> 6;
    const int l16 = lane & 15, quad = lane >> 4;
    const int qr0 = qbase + wave * 16;             // group0 query rows
    const int qr1 = qr0 + 64;                      // group1 query rows

    const bf16* Qp = qb + (size_t)bh * T_SEQ * DK;
    const bf16* Kp = kb + (size_t)bh * T_SEQ * DK;
    const bf16* Vp = vt + (size_t)bh * DK * T_SEQ;
    char* Pw = (char*)&Pl[wave][0];

    // ones B-fragment for the l row-sum MFMA
    const short one_bits = 0x3F80;
    const bf16x8 ones = {one_bits, one_bits, one_bits, one_bits,
                         one_bits, one_bits, one_bits, one_bits};

    // Q as B-operand: n = query = l16, k = dk = quad*8+j (+32 per kstep)
    bf16x8 qf[2][2];
#pragma unroll
    for (int s = 0; s < 2; ++s) {
        qf[0][s] = *(const bf16x8*)(Qp + (size_t)(qr0 + l16) * DK + s * 32 + quad * 8);
        qf[1][s] = *(const bf16x8*)(Qp + (size_t)(qr1 + l16) * DK + s * 32 + quad * 8);
    }

    // stage row-major 64x64 tile with XOR-swizzled 16B col-blocks
    auto stage = [&](int bb, int k0) {
        int j = tid;
#pragma unroll
        for (int i = 0; i < 2; ++i, j += 256) {
            int row = j >> 3, cbl = (j & 7) ^ ((j >> 3) & 7);
            load_lds16(Kp + (size_t)(k0 + row) * DK + cbl * 8, (char*)Ks[bb] + j * 16);
        }
        j = tid;
#pragma unroll
        for (int i = 0; i < 2; ++i, j += 256) {
            int row = j >> 3, cbl = (j & 7) ^ ((j >> 3) & 7);
            load_lds16(Vp + (size_t)row * T_SEQ + k0 + cbl * 8, (char*)Vs[bb] + j * 16);
        }
    };

    f32x4 o0[4] = {}, o1[4] = {};
    f32x4 ol0 = {}, ol1 = {};      // l row-sums (same C-rows as o*[j])
    const int sw0 = (quad ^ (l16 & 7)) * 8;
    const int sw1 = ((4 + quad) ^ (l16 & 7)) * 8;
    // P buffer addressing (bytes): row=l16 (128B), XOR-swizzled 16B blocks
    const int pw_wr_base = l16 * 128 + (quad & 1) * 8;   // + swizzled block
    const int pq = quad >> 1;

    int cur = 0;
    stage(0, it0 * 64);
    for (int it = it0; it <= it1; ++it) {
        __syncthreads();                      // drains DMA for cur + syncs waves
        if (it < it1) stage(cur ^ 1, (it + 1) * 64);

        const int k0 = it * 64;
        const bool skip0 = (k0 > qr0 + 15);             // wave-uniform
        const bool diag0 = (k0 + 63 > qr0) && !skip0;
        const bool diag1 = (k0 + 63 > qr1);             // skip1 never happens

        // S^T = K Q^T over 64 keys; kf fragments shared by both groups
        f32x4 s0[4] = {}, s1[4] = {};
        __builtin_amdgcn_s_setprio(1);
#pragma unroll
        for (int nt = 0; nt < 4; ++nt) {
            bf16x8 kf0 = *(const bf16x8*)(Ks[cur] + (nt * 16 + l16) * 64 + sw0);
            bf16x8 kf1 = *(const bf16x8*)(Ks[cur] + (nt * 16 + l16) * 64 + sw1);
            if (!skip0) {
                s0[nt] = __builtin_amdgcn_mfma_f32_16x16x32_bf16(kf0, qf[0][0], s0[nt], 0, 0, 0);
                s0[nt] = __builtin_amdgcn_mfma_f32_16x16x32_bf16(kf1, qf[0][1], s0[nt], 0, 0, 0);
            }
            s1[nt] = __builtin_amdgcn_mfma_f32_16x16x32_bf16(kf0, qf[1][0], s1[nt], 0, 0, 0);
            s1[nt] = __builtin_amdgcn_mfma_f32_16x16x32_bf16(kf1, qf[1][1], s1[nt], 0, 0, 0);
        }
        __builtin_amdgcn_s_setprio(0);

        // ---- group 0: exp -> P buffer -> PV (+ l-sum MFMA) ----
        if (!skip0) {
#pragma unroll
            for (int nt = 0; nt < 4; ++nt) {
                union { bf16 hv[4]; uint2 u; } pk;
#pragma unroll
                for (int r = 0; r < 4; ++r) {
                    float v = s0[nt][r];
                    if (diag0 && (k0 + nt * 16 + quad * 4 + r > qr0 + l16)) v = -30.0f;
                    pk.hv[r] = __float2bfloat16(exp2f(v));
                }
                *(uint2*)(Pw + pw_wr_base + (((nt * 2 + pq) ^ (l16 & 7)) << 4)) = pk.u;
            }
            __builtin_amdgcn_s_setprio(1);
#pragma unroll
            for (int ks = 0; ks < 2; ++ks) {
                bf16x8 pf = *(const bf16x8*)(Pw + l16 * 128 + (((ks * 4 + quad) ^ (l16 & 7)) << 4));
                const int sw = ks ? sw1 : sw0;
                ol0 = __builtin_amdgcn_mfma_f32_16x16x32_bf16(pf, ones, ol0, 0, 0, 0);
#pragma unroll
                for (int j = 0; j < 4; ++j) {
                    bf16x8 vf = *(const bf16x8*)(Vs[cur] + (j * 16 + l16) * 64 + sw);
                    o0[j] = __builtin_amdgcn_mfma_f32_16x16x32_bf16(pf, vf, o0[j], 0, 0, 0);
                }
            }
            __builtin_amdgcn_s_setprio(0);
        }

        // ---- group 1: exp -> P buffer (reused; per-wave DS pipe is in-order,
        // so these writes cannot pass g0's pf reads) -> PV (+ l-sum MFMA) ----
#pragma unroll
        for (int nt = 0; nt < 4; ++nt) {
            union { bf16 hv[4]; uint2 u; } pk;
#pragma unroll
            for (int r = 0; r < 4; ++r) {
                float v = s1[nt][r];
                if (diag1 && (k0 + nt * 16 + quad * 4 + r > qr1 + l16)) v = -30.0f;
                pk.hv[r] = __float2bfloat16(exp2f(v));
            }
            *(uint2*)(Pw + pw_wr_base + (((nt * 2 + pq) ^ (l16 & 7)) << 4)) = pk.u;
        }
        __builtin_amdgcn_s_setprio(1);
#pragma unroll
        for (int ks = 0; ks < 2; ++ks) {
            bf16x8 pf = *(const bf16x8*)(Pw + l16 * 128 + (((ks * 4 + quad) ^ (l16 & 7)) << 4));
            const int sw = ks ? sw1 : sw0;
            ol1 = __builtin_amdgcn_mfma_f32_16x16x32_bf16(pf, ones, ol1, 0, 0, 0);
#pragma unroll
            for (int j = 0; j < 4; ++j) {
                bf16x8 vf = *(const bf16x8*)(Vs[cur] + (j * 16 + l16) * 64 + sw);
                o1[j] = __builtin_amdgcn_mfma_f32_16x16x32_bf16(pf, vf, o1[j], 0, 0, 0);
            }
        }
        __builtin_amdgcn_s_setprio(0);
        cur ^= 1;
    }

    // epilogue: ol*[r] is the full l for query qr + quad*4 + r (no shuffles)
#pragma unroll
    for (int g = 0; g < 2; ++g) {
        const f32x4* op = g ? o1 : o0;
        const f32x4 lv = g ? ol1 : ol0;
        const int qr = g ? qr1 : qr0;
        if (!partial) {
#pragma unroll
            for (int r = 0; r < 4; ++r) {
                float inv_l = 1.0f / lv[r];
                int t = qr + quad * 4 + r;
#pragma unroll
                for (int j = 0; j < 4; ++j)
                    conc[((size_t)b * T_SEQ + t) * DMODEL + h * DK + j * 16 + l16] =
                        __float2bfloat16(op[j][r] * inv_l);
            }
        } else {
#pragma unroll
            for (int r = 0; r < 4; ++r) {
                int q = qr + quad * 4 + r;
                if (l16 == 0)
                    atomicAdd(&Lacc[(size_t)bh * 1024 + q - 1024], lv[r]);
                float* Ob = Oacc + ((size_t)bh * 1024 + q - 1024) * DK;
#pragma unroll
                for (int j = 0; j < 4; ++j)
                    atomicAdd(&Ob[j * 16 + l16], op[j][r]);
            }
        }
    }
}

// ---------------- normalize + concat (only q in [1024, 2048)) ----------------
__global__ void attn_finalize(const float* __restrict__ Oacc, const float* __restrict__ Lacc,
                              bf16* __restrict__ conc) {
    int i4 = blockIdx.x * blockDim.x + threadIdx.x;   // float4 units, 0..512K-1
    if (i4 >= (1 << 19)) return;
    int bhq = i4 >> 4;          // bh*1024 + q1
    int d4  = i4 & 15;
    int bh = bhq >> 10, q1 = bhq & 1023;
    int b = bh >> 4, h = bh & 15;
    int q = 1024 + q1;
    float inv = 1.0f / Lacc[bhq];
    float4 o4 = ((const float4*)Oacc)[i4];
    ushort4 u;
    u.x = __bfloat16_as_ushort(__float2bfloat16(o4.x * inv));
    u.y = __bfloat16_as_ushort(__float2bfloat16(o4.y * inv));
    u.z = __bfloat16_as_ushort(__float2bfloat16(o4.z * inv));
    u.w = __bfloat16_as_ushort(__float2bfloat16(o4.w * inv));
    *(ushort4*)&conc[((size_t)(b * T_SEQ + q)) * DMODEL + h * DK + d4 * 4] = u;
}

extern "C" void kernel_launch(void* const* d_in, const int* in_sizes, int n_in,
                              void* d_out, int out_size, void* d_ws, size_t ws_size,
                              hipStream_t stream) {
    const float* x  = (const float*)d_in[0];
    const float* wq = (const float*)d_in[1];
    const float* wk = (const float*)d_in[2];
    const float* wv = (const float*)d_in[3];
    const float* wo = (const float*)d_in[4];
    float* out = (float*)d_out;

    char* ws = (char*)d_ws;
    bf16* xb    = (bf16*)(ws);                      // 8 MiB  (4096x1024)
    bf16* wqkvb = (bf16*)(ws + (8ull << 20));       // 6 MiB  (3072x1024)
    bf16* wob   = (bf16*)(ws + (14ull << 20));      // 2 MiB  (1024x1024)
    bf16* conc  = (bf16*)(ws + (16ull << 20));      // 8 MiB
    float* Oacc = (float*)(ws + (24ull << 20));     // 8 MiB
    float* Lacc = (float*)(ws + (32ull << 20));     // 128 KiB (contiguous after Oacc)
    bf16* qb    = (bf16*)(ws + (40ull << 20));      // 8 MiB
    bf16* kb    = (bf16*)(ws + (48ull << 20));      // 8 MiB
    bf16* vt    = (bf16*)(ws + (56ull << 20));      // 8 MiB

    // 8192 cvt blocks + 2080 zero blocks (Oacc 8 MiB + Lacc 128 KiB)
    cvt_all<<<10272, 256, 0, stream>>>(x, wq, wk, wv, wo, xb, wqkvb, wob,
                                       (float4*)Oacc);
    gemm_qkv_rope<<<dim3(24, 32), 256, 0, stream>>>(xb, wqkvb, qb, kb, vt);

    attn_kernel<<<dim3(24, 32), 256, 0, stream>>>(qb, kb, vt, Oacc, Lacc, conc);
    attn_finalize<<<2048, 256, 0, stream>>>(Oacc, Lacc, conc);

    gemm_bt<<<dim3(8, 32), 256, 0, stream>>>(conc, wob, out, 4096, 1024, 1024);
}

// Round 12
// 179.542 us; speedup vs baseline: 1.1363x; 1.0081x over previous
//
#include <hip/hip_runtime.h>
#include <hip/hip_bf16.h>

typedef __hip_bfloat16 bf16;
typedef __attribute__((ext_vector_type(8))) short bf16x8;
typedef __attribute__((ext_vector_type(4))) float f32x4;

#define T_SEQ 2048
#define NHEADS 16
#define DK 64
#define DMODEL 1024

__device__ inline void load_lds16(const void* g, void* l) {
    __builtin_amdgcn_global_load_lds((const __attribute__((address_space(1))) void*)g,
                                     (__attribute__((address_space(3))) void*)l, 16, 0, 0);
}

// ---- fp32 -> bf16 convert (x + weights) + zero-fill of Oacc/Lacc tail ------
__global__ void cvt_all(const float* __restrict__ x,  const float* __restrict__ wq,
                        const float* __restrict__ wk, const float* __restrict__ wv,
                        const float* __restrict__ wo, bf16* __restrict__ xb,
                        bf16* __restrict__ wqkvb, bf16* __restrict__ wob,
                        float4* __restrict__ zacc) {
    int i = blockIdx.x * blockDim.x + threadIdx.x;
    if (i >= (1 << 21)) {                            // zero tail: Oacc+Lacc
        zacc[i - (1 << 21)] = make_float4(0.f, 0.f, 0.f, 0.f);
        return;
    }
    const float* src; bf16* dst; int off;
    if (i < (1 << 20)) { src = x; dst = xb; off = i; }
    else {
        int j = i - (1 << 20);
        int seg = j >> 18; off = j & ((1 << 18) - 1);
        src = (seg == 0) ? wq : (seg == 1) ? wk : (seg == 2) ? wv : wo;
        dst = (seg < 3) ? (wqkvb + ((size_t)seg << 20)) : wob;
    }
    float4 f = ((const float4*)src)[off];
    ushort4 o;
    o.x = __bfloat16_as_ushort(__float2bfloat16(f.x));
    o.y = __bfloat16_as_ushort(__float2bfloat16(f.y));
    o.z = __bfloat16_as_ushort(__float2bfloat16(f.z));
    o.w = __bfloat16_as_ushort(__float2bfloat16(f.w));
    ((ushort4*)dst)[off] = o;
}

// ---------------- GEMM1: qkv = x * Wqkv^T, fused RoPE + head split ----------
// v20 (swapped MFMA operands, register-local RoPE pairs) — unchanged.
__global__ __launch_bounds__(256, 4) void gemm_qkv_rope(const bf16* __restrict__ A,
                                                        const bf16* __restrict__ B,
                                                        bf16* __restrict__ qb,
                                                        bf16* __restrict__ kb,
                                                        bf16* __restrict__ vt) {
    const int K = 1024;
    __shared__ bf16 As[128 * 64];
    __shared__ bf16 Bs[128 * 64];
    const int tid  = threadIdx.x;
    const int lane = tid & 63;
    const int wave = tid >> 6;
    const int l16  = lane & 15;
    const int quad = lane >> 4;
    const int wy = wave >> 1, wx = wave & 1;
    const int brow = blockIdx.y * 128;
    const int bcol = blockIdx.x * 128;
    const int sw0 = (quad ^ (l16 & 7)) * 8;
    const int sw1 = ((4 + quad) ^ (l16 & 7)) * 8;

    f32x4 acc[4][4] = {};

    for (int k0 = 0; k0 < K; k0 += 64) {
#pragma unroll
        for (int i = 0; i < 4; ++i) {
            int j   = tid + 256 * i;                  // 0..1023
            int row = j >> 3;
            int blk = (j & 7) ^ (row & 7);            // pre-swizzled source blk
            load_lds16(A + (size_t)(brow + row) * K + k0 + blk * 8, (char*)As + j * 16);
            load_lds16(B + (size_t)(bcol + row) * K + k0 + blk * 8, (char*)Bs + j * 16);
        }
        __syncthreads();
#pragma unroll
        for (int ks = 0; ks < 2; ++ks) {
            const int sw = ks ? sw1 : sw0;
            bf16x8 af[4], bq[4];
#pragma unroll
            for (int i = 0; i < 4; ++i)
                af[i] = *(const bf16x8*)(As + (wy * 64 + i * 16 + l16) * 64 + sw);
#pragma unroll
            for (int j = 0; j < 4; ++j)
                bq[j] = *(const bf16x8*)(Bs + (wx * 64 + j * 16 + l16) * 64 + sw);
#pragma unroll
            for (int i = 0; i < 4; ++i)
#pragma unroll
                for (int j = 0; j < 4; ++j)
                    acc[i][j] = __builtin_amdgcn_mfma_f32_16x16x32_bf16(bq[j], af[i], acc[i][j], 0, 0, 0);
        }
        __syncthreads();
    }
    const int seg = bcol >> 10;                       // uniform per block
    const int hh  = ((bcol & 1023) >> 6) + wx;        // head index
    if (seg < 2) {
        bf16* dst = seg ? kb : qb;
        // q pre-scaled so attn computes p = exp2(q'.k) directly
        const float osc = seg ? 1.0f : 0.18033688011112042f;  // log2(e)/8
#pragma unroll
        for (int i = 0; i < 4; ++i) {
            int trow = brow + wy * 64 + i * 16 + l16;
            int t = trow & (T_SEQ - 1), bi = trow >> 11;
            float tf = (float)t;
            bf16* base = dst + ((size_t)(bi * NHEADS + hh) * T_SEQ + t) * DK;
#pragma unroll
            for (int j = 0; j < 4; ++j) {
                ushort4 u;
#pragma unroll
                for (int p = 0; p < 2; ++p) {
                    // d_pair = j*8 + quad*2 + p ; inv = 1000^(-d_pair/32)
                    const float inv = exp2f(-0.31143075889f * (float)(j * 8 + quad * 2 + p));
                    float s, c;
                    __sincosf(tf * inv, &s, &c);
                    float xe = acc[i][j][2 * p], xo = acc[i][j][2 * p + 1];
                    float re = fmaf(-xo, s, xe * c) * osc;
                    float ro = fmaf(xe, s, xo * c) * osc;
                    ((unsigned short*)&u)[2 * p] =
                        __bfloat16_as_ushort(__float2bfloat16(re));
                    ((unsigned short*)&u)[2 * p + 1] =
                        __bfloat16_as_ushort(__float2bfloat16(ro));
                }
                *(ushort4*)(base + j * 16 + quad * 4) = u;   // 4 consecutive d
            }
        }
    } else {
        // v: lane dim (l16 over i) = t -> coalesced vt stores (v14-verified)
#pragma unroll
        for (int j = 0; j < 4; ++j)
#pragma unroll
            for (int i = 0; i < 4; ++i)
#pragma unroll
                for (int r = 0; r < 4; ++r) {
                    int d    = j * 16 + quad * 4 + r;          // dk within head
                    int tcol = brow + wy * 64 + i * 16 + l16;
                    int t = tcol & (T_SEQ - 1), bi = tcol >> 11;
                    vt[((size_t)(bi * NHEADS + hh) * DK + d) * T_SEQ + t] =
                        __float2bfloat16(acc[i][j][r]);
                }
    }
}

// ---------------- GEMM: C[M,N] = A[M,K] * B[N,K]^T (fp32 out) ----------------
// v16 (BN=128) — unchanged.
__global__ __launch_bounds__(256, 4) void gemm_bt(const bf16* __restrict__ A,
                                                  const bf16* __restrict__ B,
                                                  float* __restrict__ C,
                                                  int M, int N, int K) {
    __shared__ bf16 As[128 * 64];
    __shared__ bf16 Bs[128 * 64];
    const int tid  = threadIdx.x;
    const int lane = tid & 63;
    const int wave = tid >> 6;
    const int l16  = lane & 15;
    const int quad = lane >> 4;
    const int wy = wave >> 1, wx = wave & 1;
    const int brow = blockIdx.y * 128;
    const int bcol = blockIdx.x * 128;
    const int sw0 = (quad ^ (l16 & 7)) * 8;
    const int sw1 = ((4 + quad) ^ (l16 & 7)) * 8;

    f32x4 acc[4][4] = {};

    for (int k0 = 0; k0 < K; k0 += 64) {
#pragma unroll
        for (int i = 0; i < 4; ++i) {
            int j   = tid + 256 * i;
            int row = j >> 3;
            int blk = (j & 7) ^ (row & 7);
            load_lds16(A + (size_t)(brow + row) * K + k0 + blk * 8, (char*)As + j * 16);
            load_lds16(B + (size_t)(bcol + row) * K + k0 + blk * 8, (char*)Bs + j * 16);
        }
        __syncthreads();
#pragma unroll
        for (int ks = 0; ks < 2; ++ks) {
            const int sw = ks ? sw1 : sw0;
            bf16x8 af[4], bq[4];
#pragma unroll
            for (int i = 0; i < 4; ++i)
                af[i] = *(const bf16x8*)(As + (wy * 64 + i * 16 + l16) * 64 + sw);
#pragma unroll
            for (int j = 0; j < 4; ++j)
                bq[j] = *(const bf16x8*)(Bs + (wx * 64 + j * 16 + l16) * 64 + sw);
#pragma unroll
            for (int i = 0; i < 4; ++i)
#pragma unroll
                for (int j = 0; j < 4; ++j)
                    acc[i][j] = __builtin_amdgcn_mfma_f32_16x16x32_bf16(af[i], bq[j], acc[i][j], 0, 0, 0);
        }
        __syncthreads();
    }
#pragma unroll
    for (int i = 0; i < 4; ++i)
#pragma unroll
        for (int j = 0; j < 4; ++j)
#pragma unroll
            for (int r = 0; r < 4; ++r) {
                int row = brow + wy * 64 + i * 16 + quad * 4 + r;
                int col = bcol + wx * 64 + j * 16 + l16;
                C[(size_t)row * N + col] = acc[i][j][r];
            }
}

// ---------------- flash attention v21: counted-vmcnt 2-deep pipeline --------
// v12 compute body + v16 schedule unchanged. Sync structure (T4): prologue
// stages BOTH buffers; per iter: s_waitcnt vmcnt(4) (own 4 staging loads for
// cur land; next's 4 stay in flight through compute) -> raw s_barrier (NO
// drain; each wave waited its own loads, so post-barrier the buffer is fully
// landed) -> compute -> sched_barrier fence -> raw s_barrier -> stage(it+2).
// Replaces __syncthreads' vmcnt(0) drain that killed the prefetch each iter.
__constant__ unsigned char c_sched[24] = {
    28, 61, 57, 58, 24, 53, 49, 20,
    62, 54, 50, 41, 42, 16, 45, 46,
     0,  4,  8, 12, 33, 37, 34, 38};

__global__ __launch_bounds__(256, 4) void attn_kernel(const bf16* __restrict__ qb,
                                                      const bf16* __restrict__ kb,
                                                      const bf16* __restrict__ vt,
                                                      float* __restrict__ Oacc,
                                                      float* __restrict__ Lacc,
                                                      bf16* __restrict__ conc) {
    __shared__ bf16 Ks[2][64 * 64];                // 2 x 8 KB
    __shared__ bf16 Vs[2][64 * 64];                // 2 x 8 KB
    __shared__ bf16 Pl[4][16 * 64];                // 8 KB (per-wave, shared g0/g1)
    const int bh = blockIdx.y;
    const int b = bh >> 4, h = bh & 15;

    const int e    = c_sched[blockIdx.x];
    const int tile = e >> 2, mode = e & 3;
    const int it0  = (mode == 2) ? tile + 1 : 0;
    const int it1  = (mode == 1) ? tile : 2 * tile + 1;
    const bool partial = (mode != 0);
    const int qbase = tile << 7;                   // 128 queries per tile

    const int tid = threadIdx.x;
    const int lane = tid & 63, wave = tid >> 6;
    const int l16 = lane & 15, quad = lane >> 4;
    const int qr0 = qbase + wave * 16;             // group0 query rows
    const int qr1 = qr0 + 64;                      // group1 query rows

    const bf16* Qp = qb + (size_t)bh * T_SEQ * DK;
    const bf16* Kp = kb + (size_t)bh * T_SEQ * DK;
    const bf16* Vp = vt + (size_t)bh * DK * T_SEQ;
    char* Pw = (char*)&Pl[wave][0];

    // ones B-fragment for the l row-sum MFMA
    const short one_bits = 0x3F80;
    const bf16x8 ones = {one_bits, one_bits, one_bits, one_bits,
                         one_bits, one_bits, one_bits, one_bits};

    // Q as B-operand: n = query = l16, k = dk = quad*8+j (+32 per kstep)
    bf16x8 qf[2][2];
#pragma unroll
    for (int s = 0; s < 2; ++s) {
        qf[0][s] = *(const bf16x8*)(Qp + (size_t)(qr0 + l16) * DK + s * 32 + quad * 8);
        qf[1][s] = *(const bf16x8*)(Qp + (size_t)(qr1 + l16) * DK + s * 32 + quad * 8);
    }

    // stage row-major 64x64 tile with XOR-swizzled 16B col-blocks.
    // 4 load_lds16 per THREAD per stage -> vmcnt delta of 4 per stage per wave.
    auto stage = [&](int bb, int k0) {
        int j = tid;
#pragma unroll
        for (int i = 0; i < 2; ++i, j += 256) {
            int row = j >> 3, cbl = (j & 7) ^ ((j >> 3) & 7);
            load_lds16(Kp + (size_t)(k0 + row) * DK + cbl * 8, (char*)Ks[bb] + j * 16);
        }
        j = tid;
#pragma unroll
        for (int i = 0; i < 2; ++i, j += 256) {
            int row = j >> 3, cbl = (j & 7) ^ ((j >> 3) & 7);
            load_lds16(Vp + (size_t)row * T_SEQ + k0 + cbl * 8, (char*)Vs[bb] + j * 16);
        }
    };

    f32x4 o0[4] = {}, o1[4] = {};
    f32x4 ol0 = {}, ol1 = {};      // l row-sums (same C-rows as o*[j])
    const int sw0 = (quad ^ (l16 & 7)) * 8;
    const int sw1 = ((4 + quad) ^ (l16 & 7)) * 8;
    // P buffer addressing (bytes): row=l16 (128B), XOR-swizzled 16B blocks
    const int pw_wr_base = l16 * 128 + (quad & 1) * 8;   // + swizzled block
    const int pq = quad >> 1;

    int cur = 0;
    stage(0, it0 * 64);
    if (it0 < it1) stage(1, (it0 + 1) * 64);
    for (int it = it0; it <= it1; ++it) {
        // wait OWN staging loads for cur (oldest 4); next tile's 4 keep flying
        if (it < it1) asm volatile("s_waitcnt vmcnt(4)" ::: "memory");
        else          asm volatile("s_waitcnt vmcnt(0)" ::: "memory");
        __builtin_amdgcn_s_barrier();          // all waves' cur loads landed
        __builtin_amdgcn_sched_barrier(0);     // pin ds_reads below barrier

        const int k0 = it * 64;
        const bool skip0 = (k0 > qr0 + 15);             // wave-uniform
        const bool diag0 = (k0 + 63 > qr0) && !skip0;
        const bool diag1 = (k0 + 63 > qr1);             // skip1 never happens

        // S^T = K Q^T over 64 keys; kf fragments shared by both groups
        f32x4 s0[4] = {}, s1[4] = {};
        __builtin_amdgcn_s_setprio(1);
#pragma unroll
        for (int nt = 0; nt < 4; ++nt) {
            bf16x8 kf0 = *(const bf16x8*)(Ks[cur] + (nt * 16 + l16) * 64 + sw0);
            bf16x8 kf1 = *(const bf16x8*)(Ks[cur] + (nt * 16 + l16) * 64 + sw1);
            if (!skip0) {
                s0[nt] = __builtin_amdgcn_mfma_f32_16x16x32_bf16(kf0, qf[0][0], s0[nt], 0, 0, 0);
                s0[nt] = __builtin_amdgcn_mfma_f32_16x16x32_bf16(kf1, qf[0][1], s0[nt], 0, 0, 0);
            }
            s1[nt] = __builtin_amdgcn_mfma_f32_16x16x32_bf16(kf0, qf[1][0], s1[nt], 0, 0, 0);
            s1[nt] = __builtin_amdgcn_mfma_f32_16x16x32_bf16(kf1, qf[1][1], s1[nt], 0, 0, 0);
        }
        __builtin_amdgcn_s_setprio(0);

        // ---- group 0: exp -> P buffer -> PV (+ l-sum MFMA) ----
        if (!skip0) {
#pragma unroll
            for (int nt = 0; nt < 4; ++nt) {
                union { bf16 hv[4]; uint2 u; } pk;
#pragma unroll
                for (int r = 0; r < 4; ++r) {
                    float v = s0[nt][r];
                    if (diag0 && (k0 + nt * 16 + quad * 4 + r > qr0 + l16)) v = -30.0f;
                    pk.hv[r] = __float2bfloat16(exp2f(v));
                }
                *(uint2*)(Pw + pw_wr_base + (((nt * 2 + pq) ^ (l16 & 7)) << 4)) = pk.u;
            }
            __builtin_amdgcn_s_setprio(1);
#pragma unroll
            for (int ks = 0; ks < 2; ++ks) {
                bf16x8 pf = *(const bf16x8*)(Pw + l16 * 128 + (((ks * 4 + quad) ^ (l16 & 7)) << 4));
                const int sw = ks ? sw1 : sw0;
                ol0 = __builtin_amdgcn_mfma_f32_16x16x32_bf16(pf, ones, ol0, 0, 0, 0);
#pragma unroll
                for (int j = 0; j < 4; ++j) {
                    bf16x8 vf = *(const bf16x8*)(Vs[cur] + (j * 16 + l16) * 64 + sw);
                    o0[j] = __builtin_amdgcn_mfma_f32_16x16x32_bf16(pf, vf, o0[j], 0, 0, 0);
                }
            }
            __builtin_amdgcn_s_setprio(0);
        }

        // ---- group 1: exp -> P buffer (reused; per-wave DS pipe is in-order,
        // so these writes cannot pass g0's pf reads) -> PV (+ l-sum MFMA) ----
#pragma unroll
        for (int nt = 0; nt < 4; ++nt) {
            union { bf16 hv[4]; uint2 u; } pk;
#pragma unroll
            for (int r = 0; r < 4; ++r) {
                float v = s1[nt][r];
                if (diag1 && (k0 + nt * 16 + quad * 4 + r > qr1 + l16)) v = -30.0f;
                pk.hv[r] = __float2bfloat16(exp2f(v));
            }
            *(uint2*)(Pw + pw_wr_base + (((nt * 2 + pq) ^ (l16 & 7)) << 4)) = pk.u;
        }
        __builtin_amdgcn_s_setprio(1);
#pragma unroll
        for (int ks = 0; ks < 2; ++ks) {
            bf16x8 pf = *(const bf16x8*)(Pw + l16 * 128 + (((ks * 4 + quad) ^ (l16 & 7)) << 4));
            const int sw = ks ? sw1 : sw0;
            ol1 = __builtin_amdgcn_mfma_f32_16x16x32_bf16(pf, ones, ol1, 0, 0, 0);
#pragma unroll
            for (int j = 0; j < 4; ++j) {
                bf16x8 vf = *(const bf16x8*)(Vs[cur] + (j * 16 + l16) * 64 + sw);
                o1[j] = __builtin_amdgcn_mfma_f32_16x16x32_bf16(pf, vf, o1[j], 0, 0, 0);
            }
        }
        __builtin_amdgcn_s_setprio(0);

        __builtin_amdgcn_sched_barrier(0);     // pin ds_reads above barrier
        __builtin_amdgcn_s_barrier();          // all waves done reading cur
        if (it + 2 <= it1) stage(cur, (it + 2) * 64);   // reuse cur for it+2
        cur ^= 1;
    }

    // epilogue: ol*[r] is the full l for query qr + quad*4 + r (no shuffles)
#pragma unroll
    for (int g = 0; g < 2; ++g) {
        const f32x4* op = g ? o1 : o0;
        const f32x4 lv = g ? ol1 : ol0;
        const int qr = g ? qr1 : qr0;
        if (!partial) {
#pragma unroll
            for (int r = 0; r < 4; ++r) {
                float inv_l = 1.0f / lv[r];
                int t = qr + quad * 4 + r;
#pragma unroll
                for (int j = 0; j < 4; ++j)
                    conc[((size_t)b * T_SEQ + t) * DMODEL + h * DK + j * 16 + l16] =
                        __float2bfloat16(op[j][r] * inv_l);
            }
        } else {
#pragma unroll
            for (int r = 0; r < 4; ++r) {
                int q = qr + quad * 4 + r;
                if (l16 == 0)
                    atomicAdd(&Lacc[(size_t)bh * 1024 + q - 1024], lv[r]);
                float* Ob = Oacc + ((size_t)bh * 1024 + q - 1024) * DK;
#pragma unroll
                for (int j = 0; j < 4; ++j)
                    atomicAdd(&Ob[j * 16 + l16], op[j][r]);
            }
        }
    }
}

// ---------------- normalize + concat (only q in [1024, 2048)) ----------------
__global__ void attn_finalize(const float* __restrict__ Oacc, const float* __restrict__ Lacc,
                              bf16* __restrict__ conc) {
    int i4 = blockIdx.x * blockDim.x + threadIdx.x;   // float4 units, 0..512K-1
    if (i4 >= (1 << 19)) return;
    int bhq = i4 >> 4;          // bh*1024 + q1
    int d4  = i4 & 15;
    int bh = bhq >> 10, q1 = bhq & 1023;
    int b = bh >> 4, h = bh & 15;
    int q = 1024 + q1;
    float inv = 1.0f / Lacc[bhq];
    float4 o4 = ((const float4*)Oacc)[i4];
    ushort4 u;
    u.x = __bfloat16_as_ushort(__float2bfloat16(o4.x * inv));
    u.y = __bfloat16_as_ushort(__float2bfloat16(o4.y * inv));
    u.z = __bfloat16_as_ushort(__float2bfloat16(o4.z * inv));
    u.w = __bfloat16_as_ushort(__float2bfloat16(o4.w * inv));
    *(ushort4*)&conc[((size_t)(b * T_SEQ + q)) * DMODEL + h * DK + d4 * 4] = u;
}

extern "C" void kernel_launch(void* const* d_in, const int* in_sizes, int n_in,
                              void* d_out, int out_size, void* d_ws, size_t ws_size,
                              hipStream_t stream) {
    const float* x  = (const float*)d_in[0];
    const float* wq = (const float*)d_in[1];
    const float* wk = (const float*)d_in[2];
    const float* wv = (const float*)d_in[3];
    const float* wo = (const float*)d_in[4];
    float* out = (float*)d_out;

    char* ws = (char*)d_ws;
    bf16* xb    = (bf16*)(ws);                      // 8 MiB  (4096x1024)
    bf16* wqkvb = (bf16*)(ws + (8ull << 20));       // 6 MiB  (3072x1024)
    bf16* wob   = (bf16*)(ws + (14ull << 20));      // 2 MiB  (1024x1024)
    bf16* conc  = (bf16*)(ws + (16ull << 20));      // 8 MiB
    float* Oacc = (float*)(ws + (24ull << 20));     // 8 MiB
    float* Lacc = (float*)(ws + (32ull << 20));     // 128 KiB (contiguous after Oacc)
    bf16* qb    = (bf16*)(ws + (40ull << 20));      // 8 MiB
    bf16* kb    = (bf16*)(ws + (48ull << 20));      // 8 MiB
    bf16* vt    = (bf16*)(ws + (56ull << 20));      // 8 MiB

    // 8192 cvt blocks + 2080 zero blocks (Oacc 8 MiB + Lacc 128 KiB)
    cvt_all<<<10272, 256, 0, stream>>>(x, wq, wk, wv, wo, xb, wqkvb, wob,
                                       (float4*)Oacc);
    gemm_qkv_rope<<<dim3(24, 32), 256, 0, stream>>>(xb, wqkvb, qb, kb, vt);

    attn_kernel<<<dim3(24, 32), 256, 0, stream>>>(qb, kb, vt, Oacc, Lacc, conc);
    attn_finalize<<<2048, 256, 0, stream>>>(Oacc, Lacc, conc);

    gemm_bt<<<dim3(8, 32), 256, 0, stream>>>(conc, wob, out, 4096, 1024, 1024);
}